// Round 1
// baseline (5205.947 us; speedup 1.0000x reference)
//
#include <hip/hip_runtime.h>

// ---------------------------------------------------------------------------
// GraphSAGE x3 (mean aggr, ReLU) + 3 fused linear heads.  N=50000, E=800000,
// IN=64, HID=128, heads 21/2/5 (concatenated to 28).
// All fp32. Aggregation = scatter-add with HW fp32 atomics, then fused
// (mean @ Wl + h @ Wr + b) GEMM per node-tile.
// ---------------------------------------------------------------------------

__global__ void deg_kernel(const int* __restrict__ dst, float* __restrict__ deg,
                           int n_edges) {
    int e = blockIdx.x * blockDim.x + threadIdx.x;
    if (e < n_edges) unsafeAtomicAdd(&deg[dst[e]], 1.0f);
}

// One thread per (edge, float4-group). Consecutive threads cover one source
// row contiguously (coalesced gather); 4 HW float atomics per thread.
template <int K>
__global__ void agg_kernel(const float* __restrict__ h, const int* __restrict__ src,
                           const int* __restrict__ dst, float* __restrict__ msum,
                           int n_edges) {
    const int GP = K / 4;
    int tid = blockIdx.x * blockDim.x + threadIdx.x;
    int e = tid / GP;
    int g = tid % GP;
    if (e >= n_edges) return;
    int s = src[e];
    int d = dst[e];
    const float4 v = reinterpret_cast<const float4*>(h + (size_t)s * K)[g];
    float* p = msum + (size_t)d * K + (size_t)g * 4;
    unsafeAtomicAdd(p + 0, v.x);
    unsafeAtomicAdd(p + 1, v.y);
    unsafeAtomicAdd(p + 2, v.z);
    unsafeAtomicAdd(p + 3, v.w);
}

// out[i,j] = act( (msum[i,:]/max(deg,1)) . Wl[:,j] + hin[i,:] . Wr[:,j] + b[j] )
// 8 nodes per 128-thread block; weights broadcast per k (L2-cached), rows in LDS.
template <int K, bool RELU>
__global__ void layer_kernel(const float* __restrict__ hin, const float* __restrict__ msum,
                             const float* __restrict__ deg, const float* __restrict__ Wl,
                             const float* __restrict__ Wr, const float* __restrict__ bias,
                             float* __restrict__ hout, int n_nodes) {
    const int NPB = 8;
    int node0 = blockIdx.x * NPB;
    int j = threadIdx.x;  // output channel 0..127
    __shared__ float sh[NPB][K];
    __shared__ float sm[NPB][K];
    for (int idx = threadIdx.x; idx < NPB * K; idx += blockDim.x) {
        int n = idx / K, k = idx % K;
        int node = node0 + n;
        if (node < n_nodes) {
            float inv = 1.0f / fmaxf(deg[node], 1.0f);
            sh[n][k] = hin[(size_t)node * K + k];
            sm[n][k] = msum[(size_t)node * K + k] * inv;
        }
    }
    __syncthreads();
    float acc[NPB];
#pragma unroll
    for (int n = 0; n < NPB; n++) acc[n] = bias[j];
    for (int k = 0; k < K; k++) {
        float wl = Wl[k * 128 + j];
        float wr = Wr[k * 128 + j];
#pragma unroll
        for (int n = 0; n < NPB; n++) acc[n] += sm[n][k] * wl + sh[n][k] * wr;
    }
#pragma unroll
    for (int n = 0; n < NPB; n++) {
        int node = node0 + n;
        if (node < n_nodes) {
            float v = RELU ? fmaxf(acc[n], 0.0f) : acc[n];
            hout[(size_t)node * 128 + j] = v;
        }
    }
}

// Build concatenated head weights: [128,21]|[128,2]|[128,5] -> [128,28]
__global__ void cat_kernel(const float* __restrict__ Wl_age, const float* __restrict__ Wl_sex,
                           const float* __restrict__ Wl_eth, const float* __restrict__ Wr_age,
                           const float* __restrict__ Wr_sex, const float* __restrict__ Wr_eth,
                           const float* __restrict__ b_age, const float* __restrict__ b_sex,
                           const float* __restrict__ b_eth, float* __restrict__ Wl_cat,
                           float* __restrict__ Wr_cat, float* __restrict__ b_cat) {
    int idx = blockIdx.x * blockDim.x + threadIdx.x;
    if (idx < 128 * 28) {
        int k = idx / 28, j = idx % 28;
        float vl, vr;
        if (j < 21) {
            vl = Wl_age[k * 21 + j];
            vr = Wr_age[k * 21 + j];
        } else if (j < 23) {
            vl = Wl_sex[k * 2 + (j - 21)];
            vr = Wr_sex[k * 2 + (j - 21)];
        } else {
            vl = Wl_eth[k * 5 + (j - 23)];
            vr = Wr_eth[k * 5 + (j - 23)];
        }
        Wl_cat[idx] = vl;
        Wr_cat[idx] = vr;
    }
    if (idx < 28) {
        b_cat[idx] = (idx < 21) ? b_age[idx] : (idx < 23) ? b_sex[idx - 21] : b_eth[idx - 23];
    }
}

// Heads: 4 nodes per 128-thread block, 32 threads per node (28 active).
__global__ void head_kernel(const float* __restrict__ h, const float* __restrict__ msum,
                            const float* __restrict__ deg, const float* __restrict__ Wl_cat,
                            const float* __restrict__ Wr_cat, const float* __restrict__ b_cat,
                            float* __restrict__ age, float* __restrict__ sex,
                            float* __restrict__ eth, int n_nodes) {
    const int NPB = 4;
    int node0 = blockIdx.x * NPB;
    __shared__ float sh[NPB][128];
    __shared__ float sm[NPB][128];
    for (int idx = threadIdx.x; idx < NPB * 128; idx += blockDim.x) {
        int n = idx >> 7, k = idx & 127;
        int node = node0 + n;
        if (node < n_nodes) {
            float inv = 1.0f / fmaxf(deg[node], 1.0f);
            sh[n][k] = h[(size_t)node * 128 + k];
            sm[n][k] = msum[(size_t)node * 128 + k] * inv;
        }
    }
    __syncthreads();
    int n = threadIdx.x >> 5, j = threadIdx.x & 31;
    int node = node0 + n;
    if (node >= n_nodes || j >= 28) return;
    float acc = b_cat[j];
    for (int k = 0; k < 128; k++)
        acc += sm[n][k] * Wl_cat[k * 28 + j] + sh[n][k] * Wr_cat[k * 28 + j];
    if (j < 21)
        age[(size_t)node * 21 + j] = acc;
    else if (j < 23)
        sex[(size_t)node * 2 + (j - 21)] = acc;
    else
        eth[(size_t)node * 5 + (j - 23)] = acc;
}

extern "C" void kernel_launch(void* const* d_in, const int* in_sizes, int n_in,
                              void* d_out, int out_size, void* d_ws, size_t ws_size,
                              hipStream_t stream) {
    const float* x        = (const float*)d_in[0];
    const int*   edge_src = (const int*)d_in[1];
    const int*   edge_dst = (const int*)d_in[2];
    const float* Wl_1 = (const float*)d_in[3];
    const float* Wr_1 = (const float*)d_in[4];
    const float* b_1  = (const float*)d_in[5];
    const float* Wl_2 = (const float*)d_in[6];
    const float* Wr_2 = (const float*)d_in[7];
    const float* b_2  = (const float*)d_in[8];
    const float* Wl_3 = (const float*)d_in[9];
    const float* Wr_3 = (const float*)d_in[10];
    const float* b_3  = (const float*)d_in[11];
    const float* Wl_age = (const float*)d_in[12];
    const float* Wr_age = (const float*)d_in[13];
    const float* b_age  = (const float*)d_in[14];
    const float* Wl_sex = (const float*)d_in[15];
    const float* Wr_sex = (const float*)d_in[16];
    const float* b_sex  = (const float*)d_in[17];
    const float* Wl_eth = (const float*)d_in[18];
    const float* Wr_eth = (const float*)d_in[19];
    const float* b_eth  = (const float*)d_in[20];

    const int n_nodes = in_sizes[0] / 64;   // 50000
    const int n_edges = in_sizes[1];        // 800000

    // Workspace layout (bytes):
    char* ws = (char*)d_ws;
    float* deg     = (float*)(ws);                          // 50000 f32
    float* msum    = (float*)(ws + 200192);                 // 50000*128 f32
    float* h       = (float*)(ws + 200192 + 25600000);      // 50000*128 f32
    float* Wl_cat  = (float*)(ws + 200192 + 2 * 25600000);  // 128*28
    float* Wr_cat  = Wl_cat + 128 * 28;
    float* b_cat   = Wr_cat + 128 * 28;

    float* out_age = (float*)d_out;
    float* out_sex = out_age + (size_t)n_nodes * 21;
    float* out_eth = out_sex + (size_t)n_nodes * 2;

    const size_t msum_bytes = (size_t)n_nodes * 128 * sizeof(float);

    // Zero deg + msum (contiguous) in one memset.
    hipMemsetAsync(d_ws, 0, 200192 + msum_bytes, stream);

    deg_kernel<<<(n_edges + 255) / 256, 256, 0, stream>>>(edge_dst, deg, n_edges);
    cat_kernel<<<(128 * 28 + 255) / 256, 256, 0, stream>>>(
        Wl_age, Wl_sex, Wl_eth, Wr_age, Wr_sex, Wr_eth, b_age, b_sex, b_eth,
        Wl_cat, Wr_cat, b_cat);

    // ---- Layer 1 (K=64): x -> h ----
    {
        int threads = n_edges * (64 / 4);
        agg_kernel<64><<<(threads + 255) / 256, 256, 0, stream>>>(x, edge_src, edge_dst, msum, n_edges);
        layer_kernel<64, true><<<(n_nodes + 7) / 8, 128, 0, stream>>>(
            x, msum, deg, Wl_1, Wr_1, b_1, h, n_nodes);
    }
    // ---- Layer 2 (K=128): h -> h (in place, row-local) ----
    {
        hipMemsetAsync(msum, 0, msum_bytes, stream);
        int threads = n_edges * (128 / 4);
        agg_kernel<128><<<(threads + 255) / 256, 256, 0, stream>>>(h, edge_src, edge_dst, msum, n_edges);
        layer_kernel<128, true><<<(n_nodes + 7) / 8, 128, 0, stream>>>(
            h, msum, deg, Wl_2, Wr_2, b_2, h, n_nodes);
    }
    // ---- Layer 3 ----
    {
        hipMemsetAsync(msum, 0, msum_bytes, stream);
        int threads = n_edges * (128 / 4);
        agg_kernel<128><<<(threads + 255) / 256, 256, 0, stream>>>(h, edge_src, edge_dst, msum, n_edges);
        layer_kernel<128, true><<<(n_nodes + 7) / 8, 128, 0, stream>>>(
            h, msum, deg, Wl_3, Wr_3, b_3, h, n_nodes);
    }
    // ---- Heads (fused 28-wide) ----
    {
        hipMemsetAsync(msum, 0, msum_bytes, stream);
        int threads = n_edges * (128 / 4);
        agg_kernel<128><<<(threads + 255) / 256, 256, 0, stream>>>(h, edge_src, edge_dst, msum, n_edges);
        head_kernel<<<(n_nodes + 3) / 4, 128, 0, stream>>>(
            h, msum, deg, Wl_cat, Wr_cat, b_cat, out_age, out_sex, out_eth, n_nodes);
    }
}

// Round 3
// 809.686 us; speedup vs baseline: 6.4296x; 6.4296x over previous
//
#include <hip/hip_runtime.h>

// ---------------------------------------------------------------------------
// GraphSAGE x3 (mean aggr, ReLU) + 3 fused linear heads.  N=50000, E=800000.
// R1 (resubmitted after infra timeout): CSR build + gather-based mean
// (no fp32 atomics), heads projected to 28ch BEFORE aggregation.
// ---------------------------------------------------------------------------

__global__ void count_kernel(const int* __restrict__ dst, int* __restrict__ degi,
                             int n_edges) {
    int e = blockIdx.x * blockDim.x + threadIdx.x;
    if (e < n_edges) atomicAdd(&degi[dst[e]], 1);
}

// Single-block exclusive scan over degi[n]; writes row_start[n+1] and cursor[n].
__global__ void scan_kernel(const int* __restrict__ degi, int* __restrict__ row_start,
                            int* __restrict__ cursor, int n) {
    __shared__ int csum[1024];
    int t = threadIdx.x;
    int chunk = (n + 1023) / 1024;
    int lo = t * chunk;
    int hi = min(lo + chunk, n);
    int s = 0;
    for (int i = lo; i < hi; ++i) s += degi[i];
    csum[t] = s;
    __syncthreads();
    // Hillis-Steele inclusive scan over the 1024 chunk sums
    for (int off = 1; off < 1024; off <<= 1) {
        int v = (t >= off) ? csum[t - off] : 0;
        __syncthreads();
        csum[t] += v;
        __syncthreads();
    }
    int run = (t == 0) ? 0 : csum[t - 1];
    for (int i = lo; i < hi; ++i) {
        row_start[i] = run;
        cursor[i] = run;
        run += degi[i];
    }
    if (t == 0) row_start[n] = csum[1023];
}

__global__ void scatter_kernel(const int* __restrict__ src, const int* __restrict__ dst,
                               int* __restrict__ cursor, int* __restrict__ col,
                               int n_edges) {
    int e = blockIdx.x * blockDim.x + threadIdx.x;
    if (e < n_edges) {
        int pos = atomicAdd(&cursor[dst[e]], 1);
        col[pos] = src[e];
    }
}

// One 64-lane wave per destination node: gather-sum neighbor rows, write mean.
// K=64: lane=channel.  K=128: lane and lane+64.
template <int K>
__global__ void agg_gather(const float* __restrict__ feat, const int* __restrict__ row_start,
                           const int* __restrict__ col, float* __restrict__ mean,
                           int n_nodes) {
    int wave = (blockIdx.x * blockDim.x + threadIdx.x) >> 6;
    int lane = threadIdx.x & 63;
    if (wave >= n_nodes) return;
    int s0 = row_start[wave];
    int s1 = row_start[wave + 1];
    float a0 = 0.f, a1 = 0.f, b0 = 0.f, b1 = 0.f;
    int e = s0;
    for (; e + 1 < s1; e += 2) {
        int sA = col[e];
        int sB = col[e + 1];
        const float* rA = feat + (size_t)sA * K;
        const float* rB = feat + (size_t)sB * K;
        a0 += rA[lane];
        b0 += rB[lane];
        if (K == 128) {
            a1 += rA[lane + 64];
            b1 += rB[lane + 64];
        }
    }
    if (e < s1) {
        const float* rA = feat + (size_t)col[e] * K;
        a0 += rA[lane];
        if (K == 128) a1 += rA[lane + 64];
    }
    int deg = s1 - s0;
    float inv = (deg > 0) ? 1.0f / (float)deg : 0.0f;
    mean[(size_t)wave * K + lane] = (a0 + b0) * inv;
    if (K == 128) mean[(size_t)wave * K + 64 + lane] = (a1 + b1) * inv;
}

// 32-lane group per node over padded [N][32] projected features.
__global__ void agg_gather32(const float* __restrict__ p, const int* __restrict__ row_start,
                             const int* __restrict__ col, float* __restrict__ meanp,
                             int n_nodes) {
    int gid = blockIdx.x * blockDim.x + threadIdx.x;
    int node = gid >> 5;
    int j = gid & 31;
    if (node >= n_nodes) return;
    int s0 = row_start[node];
    int s1 = row_start[node + 1];
    float a = 0.f, b = 0.f;
    int e = s0;
    for (; e + 1 < s1; e += 2) {
        a += p[(size_t)col[e] * 32 + j];
        b += p[(size_t)col[e + 1] * 32 + j];
    }
    if (e < s1) a += p[(size_t)col[e] * 32 + j];
    int deg = s1 - s0;
    float inv = (deg > 0) ? 1.0f / (float)deg : 0.0f;
    meanp[(size_t)node * 32 + j] = (a + b) * inv;
}

// out[i,j] = act( mean[i,:] . Wl[:,j] + hin[i,:] . Wr[:,j] + b[j] ), j=0..127
template <int K, bool RELU>
__global__ void layer_kernel(const float* __restrict__ hin, const float* __restrict__ mean,
                             const float* __restrict__ Wl, const float* __restrict__ Wr,
                             const float* __restrict__ bias, float* __restrict__ hout,
                             int n_nodes) {
    const int NPB = 8;
    int node0 = blockIdx.x * NPB;
    int j = threadIdx.x;
    __shared__ float sh[NPB][K];
    __shared__ float sm[NPB][K];
    for (int idx = threadIdx.x; idx < NPB * K; idx += blockDim.x) {
        int n = idx / K, k = idx % K;
        int node = node0 + n;
        if (node < n_nodes) {
            sh[n][k] = hin[(size_t)node * K + k];
            sm[n][k] = mean[(size_t)node * K + k];
        }
    }
    __syncthreads();
    float acc[NPB];
#pragma unroll
    for (int n = 0; n < NPB; n++) acc[n] = bias[j];
    for (int k = 0; k < K; k++) {
        float wl = Wl[k * 128 + j];
        float wr = Wr[k * 128 + j];
#pragma unroll
        for (int n = 0; n < NPB; n++) acc[n] += sm[n][k] * wl + sh[n][k] * wr;
    }
#pragma unroll
    for (int n = 0; n < NPB; n++) {
        int node = node0 + n;
        if (node < n_nodes) {
            float v = RELU ? fmaxf(acc[n], 0.0f) : acc[n];
            hout[(size_t)node * 128 + j] = v;
        }
    }
}

// Concatenate head weights: [128,21]|[128,2]|[128,5] -> [128,28] (+bias 28)
__global__ void cat_kernel(const float* __restrict__ Wl_age, const float* __restrict__ Wl_sex,
                           const float* __restrict__ Wl_eth, const float* __restrict__ Wr_age,
                           const float* __restrict__ Wr_sex, const float* __restrict__ Wr_eth,
                           const float* __restrict__ b_age, const float* __restrict__ b_sex,
                           const float* __restrict__ b_eth, float* __restrict__ Wl_cat,
                           float* __restrict__ Wr_cat, float* __restrict__ b_cat) {
    int idx = blockIdx.x * blockDim.x + threadIdx.x;
    if (idx < 128 * 28) {
        int k = idx / 28, j = idx % 28;
        float vl, vr;
        if (j < 21) {
            vl = Wl_age[k * 21 + j];
            vr = Wr_age[k * 21 + j];
        } else if (j < 23) {
            vl = Wl_sex[k * 2 + (j - 21)];
            vr = Wr_sex[k * 2 + (j - 21)];
        } else {
            vl = Wl_eth[k * 5 + (j - 23)];
            vr = Wr_eth[k * 5 + (j - 23)];
        }
        Wl_cat[idx] = vl;
        Wr_cat[idx] = vr;
    }
    if (idx < 28) {
        b_cat[idx] = (idx < 21) ? b_age[idx] : (idx < 23) ? b_sex[idx - 21] : b_eth[idx - 23];
    }
}

// p[i][j] = h[i,:] . Wl_cat[:,j]  (j<28; cols 28..31 zeroed), stride 32.
__global__ void proj_kernel(const float* __restrict__ h, const float* __restrict__ Wl_cat,
                            float* __restrict__ p, int n_nodes) {
    const int NPB = 4;
    int node0 = blockIdx.x * NPB;
    __shared__ float sh[NPB][128];
    for (int idx = threadIdx.x; idx < NPB * 128; idx += blockDim.x) {
        int n = idx >> 7, k = idx & 127;
        int node = node0 + n;
        if (node < n_nodes) sh[n][k] = h[(size_t)node * 128 + k];
    }
    __syncthreads();
    int n = threadIdx.x >> 5, j = threadIdx.x & 31;
    int node = node0 + n;
    if (node >= n_nodes) return;
    float acc = 0.f;
    if (j < 28)
        for (int k = 0; k < 128; k++) acc += sh[n][k] * Wl_cat[k * 28 + j];
    p[(size_t)node * 32 + j] = acc;
}

// out = meanp + h @ Wr_cat + b, scattered to the 3 output tensors.
__global__ void head_out_kernel(const float* __restrict__ h, const float* __restrict__ meanp,
                                const float* __restrict__ Wr_cat, const float* __restrict__ b_cat,
                                float* __restrict__ age, float* __restrict__ sex,
                                float* __restrict__ eth, int n_nodes) {
    const int NPB = 4;
    int node0 = blockIdx.x * NPB;
    __shared__ float sh[NPB][128];
    for (int idx = threadIdx.x; idx < NPB * 128; idx += blockDim.x) {
        int n = idx >> 7, k = idx & 127;
        int node = node0 + n;
        if (node < n_nodes) sh[n][k] = h[(size_t)node * 128 + k];
    }
    __syncthreads();
    int n = threadIdx.x >> 5, j = threadIdx.x & 31;
    int node = node0 + n;
    if (node >= n_nodes || j >= 28) return;
    float acc = b_cat[j] + meanp[(size_t)node * 32 + j];
    for (int k = 0; k < 128; k++) acc += sh[n][k] * Wr_cat[k * 28 + j];
    if (j < 21)
        age[(size_t)node * 21 + j] = acc;
    else if (j < 23)
        sex[(size_t)node * 2 + (j - 21)] = acc;
    else
        eth[(size_t)node * 5 + (j - 23)] = acc;
}

extern "C" void kernel_launch(void* const* d_in, const int* in_sizes, int n_in,
                              void* d_out, int out_size, void* d_ws, size_t ws_size,
                              hipStream_t stream) {
    const float* x        = (const float*)d_in[0];
    const int*   edge_src = (const int*)d_in[1];
    const int*   edge_dst = (const int*)d_in[2];
    const float* Wl_1 = (const float*)d_in[3];
    const float* Wr_1 = (const float*)d_in[4];
    const float* b_1  = (const float*)d_in[5];
    const float* Wl_2 = (const float*)d_in[6];
    const float* Wr_2 = (const float*)d_in[7];
    const float* b_2  = (const float*)d_in[8];
    const float* Wl_3 = (const float*)d_in[9];
    const float* Wr_3 = (const float*)d_in[10];
    const float* b_3  = (const float*)d_in[11];
    const float* Wl_age = (const float*)d_in[12];
    const float* Wr_age = (const float*)d_in[13];
    const float* b_age  = (const float*)d_in[14];
    const float* Wl_sex = (const float*)d_in[15];
    const float* Wr_sex = (const float*)d_in[16];
    const float* b_sex  = (const float*)d_in[17];
    const float* Wl_eth = (const float*)d_in[18];
    const float* Wr_eth = (const float*)d_in[19];
    const float* b_eth  = (const float*)d_in[20];

    const int n_nodes = in_sizes[0] / 64;   // 50000
    const int n_edges = in_sizes[1];        // 800000

    // ---- workspace layout (256-aligned offsets, ~55 MB total) ----
    char* ws = (char*)d_ws;
    int*   degi      = (int*)(ws + 0);                 // 200192
    int*   row_start = (int*)(ws + 200192);            // 200192 (n+1 ints)
    int*   cursor    = (int*)(ws + 400384);            // 200192
    int*   col       = (int*)(ws + 600576);            // 3200256
    float* Wl_cat    = (float*)(ws + 3800832);         // 14336
    float* Wr_cat    = (float*)(ws + 3815168);         // 14336
    float* b_cat     = (float*)(ws + 3829504);         // 256
    float* mean      = (float*)(ws + 3829760);         // 25600000
    float* h         = (float*)(ws + 29429760);        // 25600000
    // head phase reuses `mean` region:
    float* p     = mean;                    // [n][32] = 6.4 MB
    float* meanp = mean + (size_t)n_nodes * 32;

    float* out_age = (float*)d_out;
    float* out_sex = out_age + (size_t)n_nodes * 21;
    float* out_eth = out_sex + (size_t)n_nodes * 2;

    // ---- CSR build ----
    hipMemsetAsync(degi, 0, 200192, stream);
    count_kernel<<<(n_edges + 255) / 256, 256, 0, stream>>>(edge_dst, degi, n_edges);
    scan_kernel<<<1, 1024, 0, stream>>>(degi, row_start, cursor, n_nodes);
    scatter_kernel<<<(n_edges + 255) / 256, 256, 0, stream>>>(edge_src, edge_dst, cursor, col, n_edges);
    cat_kernel<<<(128 * 28 + 255) / 256, 256, 0, stream>>>(
        Wl_age, Wl_sex, Wl_eth, Wr_age, Wr_sex, Wr_eth, b_age, b_sex, b_eth,
        Wl_cat, Wr_cat, b_cat);

    const int agg_grid = (n_nodes + 3) / 4;       // 4 waves (nodes) per 256-thr block
    const int gemm_grid = (n_nodes + 7) / 8;

    // ---- Layer 1 (K=64): x -> h ----
    agg_gather<64><<<agg_grid, 256, 0, stream>>>(x, row_start, col, mean, n_nodes);
    layer_kernel<64, true><<<gemm_grid, 128, 0, stream>>>(x, mean, Wl_1, Wr_1, b_1, h, n_nodes);

    // ---- Layer 2 (K=128): h -> h (row-local, in place) ----
    agg_gather<128><<<agg_grid, 256, 0, stream>>>(h, row_start, col, mean, n_nodes);
    layer_kernel<128, true><<<gemm_grid, 128, 0, stream>>>(h, mean, Wl_2, Wr_2, b_2, h, n_nodes);

    // ---- Layer 3 ----
    agg_gather<128><<<agg_grid, 256, 0, stream>>>(h, row_start, col, mean, n_nodes);
    layer_kernel<128, true><<<gemm_grid, 128, 0, stream>>>(h, mean, Wl_3, Wr_3, b_3, h, n_nodes);

    // ---- Heads: project h->28 first (mean is linear), then 32-wide agg ----
    proj_kernel<<<(n_nodes + 3) / 4, 128, 0, stream>>>(h, Wl_cat, p, n_nodes);
    agg_gather32<<<(n_nodes * 32 + 255) / 256, 256, 0, stream>>>(p, row_start, col, meanp, n_nodes);
    head_out_kernel<<<(n_nodes + 3) / 4, 128, 0, stream>>>(
        h, meanp, Wr_cat, b_cat, out_age, out_sex, out_eth, n_nodes);
}

// Round 4
// 582.546 us; speedup vs baseline: 8.9365x; 1.3899x over previous
//
#include <hip/hip_runtime.h>
#include <hip/hip_bf16.h>

// ---------------------------------------------------------------------------
// GraphSAGE x3 (mean aggr, ReLU) + 3 fused heads.  N=50000, E=800000.
// R4: bf16 feature storage + MFMA (16x16x32 bf16) layer GEMMs, fp32 accum.
// CSR gather aggregation reads packed bf16x2 (halved gather bytes).
// ---------------------------------------------------------------------------

typedef __attribute__((ext_vector_type(8))) short bf16x8;
typedef __attribute__((ext_vector_type(4))) float f32x4;

__device__ __forceinline__ unsigned short f2b(float f) {
    __hip_bfloat16 h = __float2bfloat16(f);
    return *reinterpret_cast<unsigned short*>(&h);
}
__device__ __forceinline__ float b2f(unsigned short u) {
    __hip_bfloat16 h;
    *reinterpret_cast<unsigned short*>(&h) = u;
    return __bfloat162float(h);
}

// ---------------- CSR build ----------------
__global__ void count_kernel(const int* __restrict__ dst, int* __restrict__ degi,
                             int n_edges) {
    int e = blockIdx.x * blockDim.x + threadIdx.x;
    if (e < n_edges) atomicAdd(&degi[dst[e]], 1);
}

__global__ void scan_kernel(const int* __restrict__ degi, int* __restrict__ row_start,
                            int* __restrict__ cursor, int n) {
    __shared__ int csum[1024];
    int t = threadIdx.x;
    int chunk = (n + 1023) / 1024;
    int lo = t * chunk;
    int hi = min(lo + chunk, n);
    int s = 0;
    for (int i = lo; i < hi; ++i) s += degi[i];
    csum[t] = s;
    __syncthreads();
    for (int off = 1; off < 1024; off <<= 1) {
        int v = (t >= off) ? csum[t - off] : 0;
        __syncthreads();
        csum[t] += v;
        __syncthreads();
    }
    int run = (t == 0) ? 0 : csum[t - 1];
    for (int i = lo; i < hi; ++i) {
        row_start[i] = run;
        cursor[i] = run;
        run += degi[i];
    }
    if (t == 0) row_start[n] = csum[1023];
}

__global__ void scatter_kernel(const int* __restrict__ src, const int* __restrict__ dst,
                               int* __restrict__ cursor, int* __restrict__ col,
                               int n_edges) {
    int e = blockIdx.x * blockDim.x + threadIdx.x;
    if (e < n_edges) {
        int pos = atomicAdd(&cursor[dst[e]], 1);
        col[pos] = src[e];
    }
}

// ---------------- conversions / weight prep ----------------
// x fp32 -> bf16, 4 elems/thread (800000 float4 groups)
__global__ void convert_x(const float* __restrict__ x, unsigned short* __restrict__ xb,
                          int n4) {
    int t = blockIdx.x * blockDim.x + threadIdx.x;
    if (t >= n4) return;
    float4 v = reinterpret_cast<const float4*>(x)[t];
    uint2 o;
    o.x = (unsigned)f2b(v.x) | ((unsigned)f2b(v.y) << 16);
    o.y = (unsigned)f2b(v.z) | ((unsigned)f2b(v.w) << 16);
    reinterpret_cast<uint2*>(xb)[t] = o;
}

// Bt[n][k] (bf16), k<KA: Wl[k][n]; else Wr[k-KA][n].  KTOT = 2*KA.
__global__ void build_bt(const float* __restrict__ Wl, const float* __restrict__ Wr,
                         unsigned short* __restrict__ Bt, int KA) {
    int KTOT = 2 * KA;
    int idx = blockIdx.x * blockDim.x + threadIdx.x;
    if (idx >= 128 * KTOT) return;
    int n = idx / KTOT, k = idx % KTOT;
    float v = (k < KA) ? Wl[k * 128 + n] : Wr[(k - KA) * 128 + n];
    Bt[idx] = f2b(v);
}

// Concatenate head weights (fp32): [128,21]|[128,2]|[128,5] -> [128,28]
__global__ void cat_kernel(const float* __restrict__ Wl_age, const float* __restrict__ Wl_sex,
                           const float* __restrict__ Wl_eth, const float* __restrict__ Wr_age,
                           const float* __restrict__ Wr_sex, const float* __restrict__ Wr_eth,
                           const float* __restrict__ b_age, const float* __restrict__ b_sex,
                           const float* __restrict__ b_eth, float* __restrict__ Wl_cat,
                           float* __restrict__ Wr_cat, float* __restrict__ b_cat) {
    int idx = blockIdx.x * blockDim.x + threadIdx.x;
    if (idx < 128 * 28) {
        int k = idx / 28, j = idx % 28;
        float vl, vr;
        if (j < 21) {
            vl = Wl_age[k * 21 + j];
            vr = Wr_age[k * 21 + j];
        } else if (j < 23) {
            vl = Wl_sex[k * 2 + (j - 21)];
            vr = Wr_sex[k * 2 + (j - 21)];
        } else {
            vl = Wl_eth[k * 5 + (j - 23)];
            vr = Wr_eth[k * 5 + (j - 23)];
        }
        Wl_cat[idx] = vl;
        Wr_cat[idx] = vr;
    }
    if (idx < 28) {
        b_cat[idx] = (idx < 21) ? b_age[idx] : (idx < 23) ? b_sex[idx - 21] : b_eth[idx - 23];
    }
}

// ---------------- bf16 gather aggregation ----------------
// K=128: one 64-lane wave per node; lane handles channel pair 2*lane,2*lane+1.
__global__ void agg128_bf(const unsigned short* __restrict__ feat,
                          const int* __restrict__ row_start, const int* __restrict__ col,
                          unsigned short* __restrict__ mean, int n_nodes) {
    int wave = (blockIdx.x * blockDim.x + threadIdx.x) >> 6;
    int lane = threadIdx.x & 63;
    if (wave >= n_nodes) return;
    int s0 = row_start[wave];
    int s1 = row_start[wave + 1];
    const unsigned* f2 = reinterpret_cast<const unsigned*>(feat);
    float a0 = 0.f, a1 = 0.f, b0 = 0.f, b1 = 0.f;
    int e = s0;
    for (; e + 1 < s1; e += 2) {
        unsigned uA = f2[(size_t)col[e] * 64 + lane];
        unsigned uB = f2[(size_t)col[e + 1] * 64 + lane];
        a0 += b2f((unsigned short)(uA & 0xffff));
        a1 += b2f((unsigned short)(uA >> 16));
        b0 += b2f((unsigned short)(uB & 0xffff));
        b1 += b2f((unsigned short)(uB >> 16));
    }
    if (e < s1) {
        unsigned uA = f2[(size_t)col[e] * 64 + lane];
        a0 += b2f((unsigned short)(uA & 0xffff));
        a1 += b2f((unsigned short)(uA >> 16));
    }
    int deg = s1 - s0;
    float inv = (deg > 0) ? 1.0f / (float)deg : 0.0f;
    unsigned o = (unsigned)f2b((a0 + b0) * inv) | ((unsigned)f2b((a1 + b1) * inv) << 16);
    reinterpret_cast<unsigned*>(mean)[(size_t)wave * 64 + lane] = o;
}

// K=64: wave per node; half-waves interleave over edges, combine via shfl.
__global__ void agg64_bf(const unsigned short* __restrict__ feat,
                         const int* __restrict__ row_start, const int* __restrict__ col,
                         unsigned short* __restrict__ mean, int n_nodes) {
    int wave = (blockIdx.x * blockDim.x + threadIdx.x) >> 6;
    int lane = threadIdx.x & 63;
    if (wave >= n_nodes) return;
    int sub = lane >> 5;       // 0/1: which edge parity
    int lp = lane & 31;        // channel pair index
    int s0 = row_start[wave];
    int s1 = row_start[wave + 1];
    const unsigned* f2 = reinterpret_cast<const unsigned*>(feat);
    float a0 = 0.f, a1 = 0.f;
    for (int e = s0 + sub; e < s1; e += 2) {
        unsigned u = f2[(size_t)col[e] * 32 + lp];
        a0 += b2f((unsigned short)(u & 0xffff));
        a1 += b2f((unsigned short)(u >> 16));
    }
    a0 += __shfl_down(a0, 32);
    a1 += __shfl_down(a1, 32);
    if (sub == 0) {
        int deg = s1 - s0;
        float inv = (deg > 0) ? 1.0f / (float)deg : 0.0f;
        unsigned o = (unsigned)f2b(a0 * inv) | ((unsigned)f2b(a1 * inv) << 16);
        reinterpret_cast<unsigned*>(mean)[(size_t)wave * 32 + lp] = o;
    }
}

// ---------------- MFMA layer GEMM ----------------
// out[i][j] = relu( [A0_i | A1_i](K) . Bt[j](K) + bias[j] ), bf16 in/out, fp32 acc.
// Block: 64 nodes x 128 ch, 256 thr (4 waves), wave w owns rows w*16..w*16+15.
template <int KTOT, int KA>
__global__ __launch_bounds__(256) void mfma_layer(
    const unsigned short* __restrict__ A0, const unsigned short* __restrict__ A1,
    const unsigned short* __restrict__ Bt, const float* __restrict__ bias,
    unsigned short* __restrict__ out, int n_nodes) {
    constexpr int KC = KTOT / 64;
    __shared__ __align__(16) unsigned short sA[64][72];   // +8 pad: 2-way banks only
    __shared__ __align__(16) unsigned short sB[128][72];
    int node0 = blockIdx.x * 64;
    int tid = threadIdx.x;
    int w = tid >> 6, lane = tid & 63;
    f32x4 acc[8] = {};
    for (int kc = 0; kc < KC; ++kc) {
        const unsigned short* Asrc;
        int kbase, aw;
        if (kc * 64 < KA) { Asrc = A0; kbase = kc * 64; aw = KA; }
        else              { Asrc = A1; kbase = kc * 64 - KA; aw = KTOT - KA; }
        {   // stage A: 64x64 bf16, 16 elems (2x uint4) per thread
            int nd = tid >> 2, k16 = (tid & 3) * 16;
            uint4 v0 = {0, 0, 0, 0}, v1 = {0, 0, 0, 0};
            int gn = node0 + nd;
            if (gn < n_nodes) {
                const uint4* src = reinterpret_cast<const uint4*>(Asrc + (size_t)gn * aw + kbase + k16);
                v0 = src[0];
                v1 = src[1];
            }
            uint4* dst = reinterpret_cast<uint4*>(&sA[nd][k16]);
            dst[0] = v0;
            dst[1] = v1;
        }
        {   // stage B: 128x64 bf16, 32 elems (4x uint4) per thread
            int n = tid >> 1, k32 = (tid & 1) * 32;
            const uint4* src = reinterpret_cast<const uint4*>(Bt + (size_t)n * KTOT + kc * 64 + k32);
            uint4* dst = reinterpret_cast<uint4*>(&sB[n][k32]);
            dst[0] = src[0];
            dst[1] = src[1];
            dst[2] = src[2];
            dst[3] = src[3];
        }
        __syncthreads();
#pragma unroll
        for (int ks = 0; ks < 2; ++ks) {
            int kl = ks * 32 + (lane >> 4) * 8;
            bf16x8 af = *reinterpret_cast<const bf16x8*>(&sA[w * 16 + (lane & 15)][kl]);
#pragma unroll
            for (int t = 0; t < 8; ++t) {
                bf16x8 bfr = *reinterpret_cast<const bf16x8*>(&sB[t * 16 + (lane & 15)][kl]);
                acc[t] = __builtin_amdgcn_mfma_f32_16x16x32_bf16(af, bfr, acc[t], 0, 0, 0);
            }
        }
        __syncthreads();
    }
    // epilogue: C/D map col=lane&15, row=(lane>>4)*4+i  [m89-verified]
    int r0 = w * 16, cq = lane >> 4, cr = lane & 15;
#pragma unroll
    for (int t = 0; t < 8; ++t) {
        int colj = t * 16 + cr;
        float bv = bias[colj];
#pragma unroll
        for (int i = 0; i < 4; ++i) {
            int node = node0 + r0 + cq * 4 + i;
            if (node < n_nodes) {
                float v = fmaxf(acc[t][i] + bv, 0.0f);
                out[(size_t)node * 128 + colj] = f2b(v);
            }
        }
    }
}

// ---------------- heads ----------------
// p[i][j] = h[i,:] . Wl_cat[:,j]  (j<28, cols 28..31 zero), fp32 out stride 32.
__global__ void proj_kernel(const unsigned short* __restrict__ h,
                            const float* __restrict__ Wl_cat, float* __restrict__ p,
                            int n_nodes) {
    const int NPB = 4;
    int node0 = blockIdx.x * NPB;
    __shared__ float sh[NPB][128];
    for (int idx = threadIdx.x; idx < NPB * 128; idx += blockDim.x) {
        int n = idx >> 7, k = idx & 127;
        int node = node0 + n;
        if (node < n_nodes) sh[n][k] = b2f(h[(size_t)node * 128 + k]);
    }
    __syncthreads();
    int n = threadIdx.x >> 5, j = threadIdx.x & 31;
    int node = node0 + n;
    if (node >= n_nodes) return;
    float acc = 0.f;
    if (j < 28)
        for (int k = 0; k < 128; k++) acc += sh[n][k] * Wl_cat[k * 28 + j];
    p[(size_t)node * 32 + j] = acc;
}

__global__ void agg_gather32(const float* __restrict__ p, const int* __restrict__ row_start,
                             const int* __restrict__ col, float* __restrict__ meanp,
                             int n_nodes) {
    int gid = blockIdx.x * blockDim.x + threadIdx.x;
    int node = gid >> 5;
    int j = gid & 31;
    if (node >= n_nodes) return;
    int s0 = row_start[node];
    int s1 = row_start[node + 1];
    float a = 0.f, b = 0.f;
    int e = s0;
    for (; e + 1 < s1; e += 2) {
        a += p[(size_t)col[e] * 32 + j];
        b += p[(size_t)col[e + 1] * 32 + j];
    }
    if (e < s1) a += p[(size_t)col[e] * 32 + j];
    int deg = s1 - s0;
    float inv = (deg > 0) ? 1.0f / (float)deg : 0.0f;
    meanp[(size_t)node * 32 + j] = (a + b) * inv;
}

__global__ void head_out_kernel(const unsigned short* __restrict__ h,
                                const float* __restrict__ meanp,
                                const float* __restrict__ Wr_cat, const float* __restrict__ b_cat,
                                float* __restrict__ age, float* __restrict__ sex,
                                float* __restrict__ eth, int n_nodes) {
    const int NPB = 4;
    int node0 = blockIdx.x * NPB;
    __shared__ float sh[NPB][128];
    for (int idx = threadIdx.x; idx < NPB * 128; idx += blockDim.x) {
        int n = idx >> 7, k = idx & 127;
        int node = node0 + n;
        if (node < n_nodes) sh[n][k] = b2f(h[(size_t)node * 128 + k]);
    }
    __syncthreads();
    int n = threadIdx.x >> 5, j = threadIdx.x & 31;
    int node = node0 + n;
    if (node >= n_nodes || j >= 28) return;
    float acc = b_cat[j] + meanp[(size_t)node * 32 + j];
    for (int k = 0; k < 128; k++) acc += sh[n][k] * Wr_cat[k * 28 + j];
    if (j < 21)
        age[(size_t)node * 21 + j] = acc;
    else if (j < 23)
        sex[(size_t)node * 2 + (j - 21)] = acc;
    else
        eth[(size_t)node * 5 + (j - 23)] = acc;
}

extern "C" void kernel_launch(void* const* d_in, const int* in_sizes, int n_in,
                              void* d_out, int out_size, void* d_ws, size_t ws_size,
                              hipStream_t stream) {
    const float* x        = (const float*)d_in[0];
    const int*   edge_src = (const int*)d_in[1];
    const int*   edge_dst = (const int*)d_in[2];
    const float* Wl_1 = (const float*)d_in[3];
    const float* Wr_1 = (const float*)d_in[4];
    const float* b_1  = (const float*)d_in[5];
    const float* Wl_2 = (const float*)d_in[6];
    const float* Wr_2 = (const float*)d_in[7];
    const float* b_2  = (const float*)d_in[8];
    const float* Wl_3 = (const float*)d_in[9];
    const float* Wr_3 = (const float*)d_in[10];
    const float* b_3  = (const float*)d_in[11];
    const float* Wl_age = (const float*)d_in[12];
    const float* Wr_age = (const float*)d_in[13];
    const float* b_age  = (const float*)d_in[14];
    const float* Wl_sex = (const float*)d_in[15];
    const float* Wr_sex = (const float*)d_in[16];
    const float* b_sex  = (const float*)d_in[17];
    const float* Wl_eth = (const float*)d_in[18];
    const float* Wr_eth = (const float*)d_in[19];
    const float* b_eth  = (const float*)d_in[20];

    const int n_nodes = in_sizes[0] / 64;   // 50000
    const int n_edges = in_sizes[1];        // 800000

    // ---- workspace layout ----
    char* ws = (char*)d_ws;
    int*            degi      = (int*)(ws + 0);                  // 200192
    int*            row_start = (int*)(ws + 200192);             // 200192
    int*            cursor    = (int*)(ws + 400384);             // 200192
    int*            col       = (int*)(ws + 600576);             // 3200256
    unsigned short* Bt1       = (unsigned short*)(ws + 3800832); // 32768
    unsigned short* Bt2       = (unsigned short*)(ws + 3833600); // 65536
    unsigned short* Bt3       = (unsigned short*)(ws + 3899136); // 65536
    float*          Wl_cat    = (float*)(ws + 3964672);          // 14336
    float*          Wr_cat    = (float*)(ws + 3979008);          // 14336
    float*          b_cat     = (float*)(ws + 3993344);          // 256
    unsigned short* xb        = (unsigned short*)(ws + 3993600); // 6400256
    unsigned short* h_bf      = (unsigned short*)(ws + 10393856);// 12800256
    unsigned short* mean_bf   = (unsigned short*)(ws + 23194112);// 12800256 ([n][128] or [n][64])
    float*          p         = (float*)(ws + 35994368);         // 6400256
    float*          meanp     = (float*)(ws + 42394624);         // 6400256

    float* out_age = (float*)d_out;
    float* out_sex = out_age + (size_t)n_nodes * 21;
    float* out_eth = out_sex + (size_t)n_nodes * 2;

    // ---- CSR build + prep ----
    hipMemsetAsync(degi, 0, 200192, stream);
    count_kernel<<<(n_edges + 255) / 256, 256, 0, stream>>>(edge_dst, degi, n_edges);
    scan_kernel<<<1, 1024, 0, stream>>>(degi, row_start, cursor, n_nodes);
    scatter_kernel<<<(n_edges + 255) / 256, 256, 0, stream>>>(edge_src, edge_dst, cursor, col, n_edges);
    convert_x<<<(n_nodes * 64 / 4 + 255) / 256, 256, 0, stream>>>(x, xb, n_nodes * 64 / 4);
    build_bt<<<(128 * 128 + 255) / 256, 256, 0, stream>>>(Wl_1, Wr_1, Bt1, 64);
    build_bt<<<(128 * 256 + 255) / 256, 256, 0, stream>>>(Wl_2, Wr_2, Bt2, 128);
    build_bt<<<(128 * 256 + 255) / 256, 256, 0, stream>>>(Wl_3, Wr_3, Bt3, 128);
    cat_kernel<<<(128 * 28 + 255) / 256, 256, 0, stream>>>(
        Wl_age, Wl_sex, Wl_eth, Wr_age, Wr_sex, Wr_eth, b_age, b_sex, b_eth,
        Wl_cat, Wr_cat, b_cat);

    const int agg_grid  = (n_nodes * 64 + 255) / 256;   // one wave per node
    const int gemm_grid = (n_nodes + 63) / 64;

    // ---- Layer 1: A = [mean(x)(64) | x(64)] ----
    agg64_bf<<<agg_grid, 256, 0, stream>>>(xb, row_start, col, mean_bf, n_nodes);
    mfma_layer<128, 64><<<gemm_grid, 256, 0, stream>>>(mean_bf, xb, Bt1, b_1, h_bf, n_nodes);

    // ---- Layer 2: A = [mean(h)(128) | h(128)] (row-local, h in place) ----
    agg128_bf<<<agg_grid, 256, 0, stream>>>(h_bf, row_start, col, mean_bf, n_nodes);
    mfma_layer<256, 128><<<gemm_grid, 256, 0, stream>>>(mean_bf, h_bf, Bt2, b_2, h_bf, n_nodes);

    // ---- Layer 3 ----
    agg128_bf<<<agg_grid, 256, 0, stream>>>(h_bf, row_start, col, mean_bf, n_nodes);
    mfma_layer<256, 128><<<gemm_grid, 256, 0, stream>>>(mean_bf, h_bf, Bt3, b_3, h_bf, n_nodes);

    // ---- Heads: project h->28 first (mean is linear), then 32-wide agg ----
    proj_kernel<<<(n_nodes + 3) / 4, 128, 0, stream>>>(h_bf, Wl_cat, p, n_nodes);
    agg_gather32<<<(n_nodes * 32 + 255) / 256, 256, 0, stream>>>(p, row_start, col, meanp, n_nodes);
    head_out_kernel<<<(n_nodes + 3) / 4, 128, 0, stream>>>(
        h_bf, meanp, Wr_cat, b_cat, out_age, out_sex, out_eth, n_nodes);
}

// Round 5
// 479.637 us; speedup vs baseline: 10.8539x; 1.2146x over previous
//
#include <hip/hip_runtime.h>
#include <hip/hip_bf16.h>

// ---------------------------------------------------------------------------
// GraphSAGE x3 (mean aggr, ReLU) + 3 fused heads.  N=50000, E=800000.
// R5: replace single-block scan (109us, one CU busy) with 3-phase parallel
// scan (~8us). Rest identical to R4 (bf16 MFMA layers, CSR gather agg).
// ---------------------------------------------------------------------------

typedef __attribute__((ext_vector_type(8))) short bf16x8;
typedef __attribute__((ext_vector_type(4))) float f32x4;

__device__ __forceinline__ unsigned short f2b(float f) {
    __hip_bfloat16 h = __float2bfloat16(f);
    return *reinterpret_cast<unsigned short*>(&h);
}
__device__ __forceinline__ float b2f(unsigned short u) {
    __hip_bfloat16 h;
    *reinterpret_cast<unsigned short*>(&h) = u;
    return __bfloat162float(h);
}

// ---------------- CSR build ----------------
__global__ void count_kernel(const int* __restrict__ dst, int* __restrict__ degi,
                             int n_edges) {
    int e = blockIdx.x * blockDim.x + threadIdx.x;
    if (e < n_edges) atomicAdd(&degi[dst[e]], 1);
}

// Phase A: per-block exclusive scan (256 elems/block) + block sums.
__global__ void scan_local(const int* __restrict__ degi, int* __restrict__ loc,
                           int* __restrict__ bsum, int n) {
    __shared__ int tmp[256];
    int i = blockIdx.x * 256 + threadIdx.x;
    int v = (i < n) ? degi[i] : 0;
    tmp[threadIdx.x] = v;
    __syncthreads();
    for (int off = 1; off < 256; off <<= 1) {
        int t = (threadIdx.x >= off) ? tmp[threadIdx.x - off] : 0;
        __syncthreads();
        tmp[threadIdx.x] += t;
        __syncthreads();
    }
    if (i < n) loc[i] = tmp[threadIdx.x] - v;  // exclusive
    if (threadIdx.x == 255) bsum[blockIdx.x] = tmp[255];
}

// Phase B: exclusive scan of the <=256 block sums, in place.
__global__ void scan_block(int* __restrict__ bsum, int nblk) {
    __shared__ int tmp[256];
    int v = (threadIdx.x < nblk) ? bsum[threadIdx.x] : 0;
    tmp[threadIdx.x] = v;
    __syncthreads();
    for (int off = 1; off < 256; off <<= 1) {
        int t = (threadIdx.x >= off) ? tmp[threadIdx.x - off] : 0;
        __syncthreads();
        tmp[threadIdx.x] += t;
        __syncthreads();
    }
    if (threadIdx.x < nblk) bsum[threadIdx.x] = tmp[threadIdx.x] - v;
}

// Phase C: row_start/cursor = loc + block offset; row_start[n] = n_edges.
__global__ void scan_add(const int* __restrict__ loc, const int* __restrict__ bsum,
                         int* __restrict__ row_start, int* __restrict__ cursor,
                         int n, int n_edges) {
    int i = blockIdx.x * 256 + threadIdx.x;
    if (i < n) {
        int r = loc[i] + bsum[blockIdx.x];
        row_start[i] = r;
        cursor[i] = r;
    }
    if (i == 0) row_start[n] = n_edges;
}

__global__ void scatter_kernel(const int* __restrict__ src, const int* __restrict__ dst,
                               int* __restrict__ cursor, int* __restrict__ col,
                               int n_edges) {
    int e = blockIdx.x * blockDim.x + threadIdx.x;
    if (e < n_edges) {
        int pos = atomicAdd(&cursor[dst[e]], 1);
        col[pos] = src[e];
    }
}

// ---------------- conversions / weight prep ----------------
__global__ void convert_x(const float* __restrict__ x, unsigned short* __restrict__ xb,
                          int n4) {
    int t = blockIdx.x * blockDim.x + threadIdx.x;
    if (t >= n4) return;
    float4 v = reinterpret_cast<const float4*>(x)[t];
    uint2 o;
    o.x = (unsigned)f2b(v.x) | ((unsigned)f2b(v.y) << 16);
    o.y = (unsigned)f2b(v.z) | ((unsigned)f2b(v.w) << 16);
    reinterpret_cast<uint2*>(xb)[t] = o;
}

// Bt[n][k] (bf16), k<KA: Wl[k][n]; else Wr[k-KA][n].  KTOT = 2*KA.
__global__ void build_bt(const float* __restrict__ Wl, const float* __restrict__ Wr,
                         unsigned short* __restrict__ Bt, int KA) {
    int KTOT = 2 * KA;
    int idx = blockIdx.x * blockDim.x + threadIdx.x;
    if (idx >= 128 * KTOT) return;
    int n = idx / KTOT, k = idx % KTOT;
    float v = (k < KA) ? Wl[k * 128 + n] : Wr[(k - KA) * 128 + n];
    Bt[idx] = f2b(v);
}

__global__ void cat_kernel(const float* __restrict__ Wl_age, const float* __restrict__ Wl_sex,
                           const float* __restrict__ Wl_eth, const float* __restrict__ Wr_age,
                           const float* __restrict__ Wr_sex, const float* __restrict__ Wr_eth,
                           const float* __restrict__ b_age, const float* __restrict__ b_sex,
                           const float* __restrict__ b_eth, float* __restrict__ Wl_cat,
                           float* __restrict__ Wr_cat, float* __restrict__ b_cat) {
    int idx = blockIdx.x * blockDim.x + threadIdx.x;
    if (idx < 128 * 28) {
        int k = idx / 28, j = idx % 28;
        float vl, vr;
        if (j < 21) {
            vl = Wl_age[k * 21 + j];
            vr = Wr_age[k * 21 + j];
        } else if (j < 23) {
            vl = Wl_sex[k * 2 + (j - 21)];
            vr = Wr_sex[k * 2 + (j - 21)];
        } else {
            vl = Wl_eth[k * 5 + (j - 23)];
            vr = Wr_eth[k * 5 + (j - 23)];
        }
        Wl_cat[idx] = vl;
        Wr_cat[idx] = vr;
    }
    if (idx < 28) {
        b_cat[idx] = (idx < 21) ? b_age[idx] : (idx < 23) ? b_sex[idx - 21] : b_eth[idx - 23];
    }
}

// ---------------- bf16 gather aggregation ----------------
__global__ void agg128_bf(const unsigned short* __restrict__ feat,
                          const int* __restrict__ row_start, const int* __restrict__ col,
                          unsigned short* __restrict__ mean, int n_nodes) {
    int wave = (blockIdx.x * blockDim.x + threadIdx.x) >> 6;
    int lane = threadIdx.x & 63;
    if (wave >= n_nodes) return;
    int s0 = row_start[wave];
    int s1 = row_start[wave + 1];
    const unsigned* f2 = reinterpret_cast<const unsigned*>(feat);
    float a0 = 0.f, a1 = 0.f, b0 = 0.f, b1 = 0.f;
    int e = s0;
    for (; e + 1 < s1; e += 2) {
        unsigned uA = f2[(size_t)col[e] * 64 + lane];
        unsigned uB = f2[(size_t)col[e + 1] * 64 + lane];
        a0 += b2f((unsigned short)(uA & 0xffff));
        a1 += b2f((unsigned short)(uA >> 16));
        b0 += b2f((unsigned short)(uB & 0xffff));
        b1 += b2f((unsigned short)(uB >> 16));
    }
    if (e < s1) {
        unsigned uA = f2[(size_t)col[e] * 64 + lane];
        a0 += b2f((unsigned short)(uA & 0xffff));
        a1 += b2f((unsigned short)(uA >> 16));
    }
    int deg = s1 - s0;
    float inv = (deg > 0) ? 1.0f / (float)deg : 0.0f;
    unsigned o = (unsigned)f2b((a0 + b0) * inv) | ((unsigned)f2b((a1 + b1) * inv) << 16);
    reinterpret_cast<unsigned*>(mean)[(size_t)wave * 64 + lane] = o;
}

__global__ void agg64_bf(const unsigned short* __restrict__ feat,
                         const int* __restrict__ row_start, const int* __restrict__ col,
                         unsigned short* __restrict__ mean, int n_nodes) {
    int wave = (blockIdx.x * blockDim.x + threadIdx.x) >> 6;
    int lane = threadIdx.x & 63;
    if (wave >= n_nodes) return;
    int sub = lane >> 5;
    int lp = lane & 31;
    int s0 = row_start[wave];
    int s1 = row_start[wave + 1];
    const unsigned* f2 = reinterpret_cast<const unsigned*>(feat);
    float a0 = 0.f, a1 = 0.f;
    for (int e = s0 + sub; e < s1; e += 2) {
        unsigned u = f2[(size_t)col[e] * 32 + lp];
        a0 += b2f((unsigned short)(u & 0xffff));
        a1 += b2f((unsigned short)(u >> 16));
    }
    a0 += __shfl_down(a0, 32);
    a1 += __shfl_down(a1, 32);
    if (sub == 0) {
        int deg = s1 - s0;
        float inv = (deg > 0) ? 1.0f / (float)deg : 0.0f;
        unsigned o = (unsigned)f2b(a0 * inv) | ((unsigned)f2b(a1 * inv) << 16);
        reinterpret_cast<unsigned*>(mean)[(size_t)wave * 32 + lp] = o;
    }
}

// ---------------- MFMA layer GEMM ----------------
template <int KTOT, int KA>
__global__ __launch_bounds__(256) void mfma_layer(
    const unsigned short* __restrict__ A0, const unsigned short* __restrict__ A1,
    const unsigned short* __restrict__ Bt, const float* __restrict__ bias,
    unsigned short* __restrict__ out, int n_nodes) {
    constexpr int KC = KTOT / 64;
    __shared__ __align__(16) unsigned short sA[64][72];
    __shared__ __align__(16) unsigned short sB[128][72];
    int node0 = blockIdx.x * 64;
    int tid = threadIdx.x;
    int w = tid >> 6, lane = tid & 63;
    f32x4 acc[8] = {};
    for (int kc = 0; kc < KC; ++kc) {
        const unsigned short* Asrc;
        int kbase, aw;
        if (kc * 64 < KA) { Asrc = A0; kbase = kc * 64; aw = KA; }
        else              { Asrc = A1; kbase = kc * 64 - KA; aw = KTOT - KA; }
        {
            int nd = tid >> 2, k16 = (tid & 3) * 16;
            uint4 v0 = {0, 0, 0, 0}, v1 = {0, 0, 0, 0};
            int gn = node0 + nd;
            if (gn < n_nodes) {
                const uint4* src = reinterpret_cast<const uint4*>(Asrc + (size_t)gn * aw + kbase + k16);
                v0 = src[0];
                v1 = src[1];
            }
            uint4* dst = reinterpret_cast<uint4*>(&sA[nd][k16]);
            dst[0] = v0;
            dst[1] = v1;
        }
        {
            int n = tid >> 1, k32 = (tid & 1) * 32;
            const uint4* src = reinterpret_cast<const uint4*>(Bt + (size_t)n * KTOT + kc * 64 + k32);
            uint4* dst = reinterpret_cast<uint4*>(&sB[n][k32]);
            dst[0] = src[0];
            dst[1] = src[1];
            dst[2] = src[2];
            dst[3] = src[3];
        }
        __syncthreads();
#pragma unroll
        for (int ks = 0; ks < 2; ++ks) {
            int kl = ks * 32 + (lane >> 4) * 8;
            bf16x8 af = *reinterpret_cast<const bf16x8*>(&sA[w * 16 + (lane & 15)][kl]);
#pragma unroll
            for (int t = 0; t < 8; ++t) {
                bf16x8 bfr = *reinterpret_cast<const bf16x8*>(&sB[t * 16 + (lane & 15)][kl]);
                acc[t] = __builtin_amdgcn_mfma_f32_16x16x32_bf16(af, bfr, acc[t], 0, 0, 0);
            }
        }
        __syncthreads();
    }
    int r0 = w * 16, cq = lane >> 4, cr = lane & 15;
#pragma unroll
    for (int t = 0; t < 8; ++t) {
        int colj = t * 16 + cr;
        float bv = bias[colj];
#pragma unroll
        for (int i = 0; i < 4; ++i) {
            int node = node0 + r0 + cq * 4 + i;
            if (node < n_nodes) {
                float v = fmaxf(acc[t][i] + bv, 0.0f);
                out[(size_t)node * 128 + colj] = f2b(v);
            }
        }
    }
}

// ---------------- heads ----------------
__global__ void proj_kernel(const unsigned short* __restrict__ h,
                            const float* __restrict__ Wl_cat, float* __restrict__ p,
                            int n_nodes) {
    const int NPB = 4;
    int node0 = blockIdx.x * NPB;
    __shared__ float sh[NPB][128];
    for (int idx = threadIdx.x; idx < NPB * 128; idx += blockDim.x) {
        int n = idx >> 7, k = idx & 127;
        int node = node0 + n;
        if (node < n_nodes) sh[n][k] = b2f(h[(size_t)node * 128 + k]);
    }
    __syncthreads();
    int n = threadIdx.x >> 5, j = threadIdx.x & 31;
    int node = node0 + n;
    if (node >= n_nodes) return;
    float acc = 0.f;
    if (j < 28)
        for (int k = 0; k < 128; k++) acc += sh[n][k] * Wl_cat[k * 28 + j];
    p[(size_t)node * 32 + j] = acc;
}

__global__ void agg_gather32(const float* __restrict__ p, const int* __restrict__ row_start,
                             const int* __restrict__ col, float* __restrict__ meanp,
                             int n_nodes) {
    int gid = blockIdx.x * blockDim.x + threadIdx.x;
    int node = gid >> 5;
    int j = gid & 31;
    if (node >= n_nodes) return;
    int s0 = row_start[node];
    int s1 = row_start[node + 1];
    float a = 0.f, b = 0.f;
    int e = s0;
    for (; e + 1 < s1; e += 2) {
        a += p[(size_t)col[e] * 32 + j];
        b += p[(size_t)col[e + 1] * 32 + j];
    }
    if (e < s1) a += p[(size_t)col[e] * 32 + j];
    int deg = s1 - s0;
    float inv = (deg > 0) ? 1.0f / (float)deg : 0.0f;
    meanp[(size_t)node * 32 + j] = (a + b) * inv;
}

__global__ void head_out_kernel(const unsigned short* __restrict__ h,
                                const float* __restrict__ meanp,
                                const float* __restrict__ Wr_cat, const float* __restrict__ b_cat,
                                float* __restrict__ age, float* __restrict__ sex,
                                float* __restrict__ eth, int n_nodes) {
    const int NPB = 4;
    int node0 = blockIdx.x * NPB;
    __shared__ float sh[NPB][128];
    for (int idx = threadIdx.x; idx < NPB * 128; idx += blockDim.x) {
        int n = idx >> 7, k = idx & 127;
        int node = node0 + n;
        if (node < n_nodes) sh[n][k] = b2f(h[(size_t)node * 128 + k]);
    }
    __syncthreads();
    int n = threadIdx.x >> 5, j = threadIdx.x & 31;
    int node = node0 + n;
    if (node >= n_nodes || j >= 28) return;
    float acc = b_cat[j] + meanp[(size_t)node * 32 + j];
    for (int k = 0; k < 128; k++) acc += sh[n][k] * Wr_cat[k * 28 + j];
    if (j < 21)
        age[(size_t)node * 21 + j] = acc;
    else if (j < 23)
        sex[(size_t)node * 2 + (j - 21)] = acc;
    else
        eth[(size_t)node * 5 + (j - 23)] = acc;
}

extern "C" void kernel_launch(void* const* d_in, const int* in_sizes, int n_in,
                              void* d_out, int out_size, void* d_ws, size_t ws_size,
                              hipStream_t stream) {
    const float* x        = (const float*)d_in[0];
    const int*   edge_src = (const int*)d_in[1];
    const int*   edge_dst = (const int*)d_in[2];
    const float* Wl_1 = (const float*)d_in[3];
    const float* Wr_1 = (const float*)d_in[4];
    const float* b_1  = (const float*)d_in[5];
    const float* Wl_2 = (const float*)d_in[6];
    const float* Wr_2 = (const float*)d_in[7];
    const float* b_2  = (const float*)d_in[8];
    const float* Wl_3 = (const float*)d_in[9];
    const float* Wr_3 = (const float*)d_in[10];
    const float* b_3  = (const float*)d_in[11];
    const float* Wl_age = (const float*)d_in[12];
    const float* Wr_age = (const float*)d_in[13];
    const float* b_age  = (const float*)d_in[14];
    const float* Wl_sex = (const float*)d_in[15];
    const float* Wr_sex = (const float*)d_in[16];
    const float* b_sex  = (const float*)d_in[17];
    const float* Wl_eth = (const float*)d_in[18];
    const float* Wr_eth = (const float*)d_in[19];
    const float* b_eth  = (const float*)d_in[20];

    const int n_nodes = in_sizes[0] / 64;   // 50000
    const int n_edges = in_sizes[1];        // 800000

    // ---- workspace layout ----
    char* ws = (char*)d_ws;
    int*            degi      = (int*)(ws + 0);                  // 200192
    int*            row_start = (int*)(ws + 200192);             // 200192
    int*            cursor    = (int*)(ws + 400384);             // 200192
    int*            col       = (int*)(ws + 600576);             // 3200256
    unsigned short* Bt1       = (unsigned short*)(ws + 3800832); // 32768
    unsigned short* Bt2       = (unsigned short*)(ws + 3833600); // 65536
    unsigned short* Bt3       = (unsigned short*)(ws + 3899136); // 65536
    float*          Wl_cat    = (float*)(ws + 3964672);          // 14336
    float*          Wr_cat    = (float*)(ws + 3979008);          // 14336
    float*          b_cat     = (float*)(ws + 3993344);          // 256
    unsigned short* xb        = (unsigned short*)(ws + 3993600); // 6400256
    unsigned short* h_bf      = (unsigned short*)(ws + 10393856);// 12800256
    unsigned short* mean_bf   = (unsigned short*)(ws + 23194112);// 12800256
    float*          p         = (float*)(ws + 35994368);         // 6400256
    float*          meanp     = (float*)(ws + 42394624);         // 6400256
    int*            scan_loc  = (int*)(ws + 48794880);           // 200192
    int*            scan_bsum = (int*)(ws + 48995072);           // 1024

    float* out_age = (float*)d_out;
    float* out_sex = out_age + (size_t)n_nodes * 21;
    float* out_eth = out_sex + (size_t)n_nodes * 2;

    const int nblk_scan = (n_nodes + 255) / 256;   // 196 (<256)

    // ---- CSR build + prep ----
    hipMemsetAsync(degi, 0, 200192, stream);
    count_kernel<<<(n_edges + 255) / 256, 256, 0, stream>>>(edge_dst, degi, n_edges);
    scan_local<<<nblk_scan, 256, 0, stream>>>(degi, scan_loc, scan_bsum, n_nodes);
    scan_block<<<1, 256, 0, stream>>>(scan_bsum, nblk_scan);
    scan_add<<<nblk_scan, 256, 0, stream>>>(scan_loc, scan_bsum, row_start, cursor,
                                            n_nodes, n_edges);
    scatter_kernel<<<(n_edges + 255) / 256, 256, 0, stream>>>(edge_src, edge_dst, cursor, col, n_edges);
    convert_x<<<(n_nodes * 64 / 4 + 255) / 256, 256, 0, stream>>>(x, xb, n_nodes * 64 / 4);
    build_bt<<<(128 * 128 + 255) / 256, 256, 0, stream>>>(Wl_1, Wr_1, Bt1, 64);
    build_bt<<<(128 * 256 + 255) / 256, 256, 0, stream>>>(Wl_2, Wr_2, Bt2, 128);
    build_bt<<<(128 * 256 + 255) / 256, 256, 0, stream>>>(Wl_3, Wr_3, Bt3, 128);
    cat_kernel<<<(128 * 28 + 255) / 256, 256, 0, stream>>>(
        Wl_age, Wl_sex, Wl_eth, Wr_age, Wr_sex, Wr_eth, b_age, b_sex, b_eth,
        Wl_cat, Wr_cat, b_cat);

    const int agg_grid  = (n_nodes * 64 + 255) / 256;
    const int gemm_grid = (n_nodes + 63) / 64;

    // ---- Layer 1: A = [mean(x)(64) | x(64)] ----
    agg64_bf<<<agg_grid, 256, 0, stream>>>(xb, row_start, col, mean_bf, n_nodes);
    mfma_layer<128, 64><<<gemm_grid, 256, 0, stream>>>(mean_bf, xb, Bt1, b_1, h_bf, n_nodes);

    // ---- Layer 2 ----
    agg128_bf<<<agg_grid, 256, 0, stream>>>(h_bf, row_start, col, mean_bf, n_nodes);
    mfma_layer<256, 128><<<gemm_grid, 256, 0, stream>>>(mean_bf, h_bf, Bt2, b_2, h_bf, n_nodes);

    // ---- Layer 3 ----
    agg128_bf<<<agg_grid, 256, 0, stream>>>(h_bf, row_start, col, mean_bf, n_nodes);
    mfma_layer<256, 128><<<gemm_grid, 256, 0, stream>>>(mean_bf, h_bf, Bt3, b_3, h_bf, n_nodes);

    // ---- Heads ----
    proj_kernel<<<(n_nodes + 3) / 4, 128, 0, stream>>>(h_bf, Wl_cat, p, n_nodes);
    agg_gather32<<<(n_nodes * 32 + 255) / 256, 256, 0, stream>>>(p, row_start, col, meanp, n_nodes);
    head_out_kernel<<<(n_nodes + 3) / 4, 128, 0, stream>>>(
        h_bf, meanp, Wr_cat, b_cat, out_age, out_sex, out_eth, n_nodes);
}

// Round 6
// 391.089 us; speedup vs baseline: 13.3114x; 1.2264x over previous
//
#include <hip/hip_runtime.h>
#include <hip/hip_bf16.h>

// ---------------------------------------------------------------------------
// GraphSAGE x3 (mean aggr, ReLU) + 3 fused heads.  N=50000, E=800000.
// R6: locality-aware CSR build (bucketed LDS counting sort -> L2-merged
// writes, LDS-atomic cursors) replacing 52us random-scatter + random-atomic
// count.  agg128: shfl-broadcast col + 4-deep ILP.
// ---------------------------------------------------------------------------

typedef __attribute__((ext_vector_type(8))) short bf16x8;
typedef __attribute__((ext_vector_type(4))) float f32x4;

#define NBSH 7          // 128 nodes per bucket
#define EPW  4096       // edges per sort chunk

__device__ __forceinline__ unsigned short f2b(float f) {
    __hip_bfloat16 h = __float2bfloat16(f);
    return *reinterpret_cast<unsigned short*>(&h);
}
__device__ __forceinline__ float b2f(unsigned short u) {
    __hip_bfloat16 h;
    *reinterpret_cast<unsigned short*>(&h) = u;
    return __bfloat162float(h);
}

// ---------------- bucketed CSR build ----------------
// (1) global bucket histogram via LDS partials
__global__ void bucket_hist(const int* __restrict__ dst, int* __restrict__ ghist,
                            int n_edges, int nb) {
    __shared__ int lh[512];
    int tid = threadIdx.x;
    for (int i = tid; i < 512; i += 256) lh[i] = 0;
    __syncthreads();
    int stride = gridDim.x * blockDim.x;
    for (int e = blockIdx.x * blockDim.x + tid; e < n_edges; e += stride)
        atomicAdd(&lh[dst[e] >> NBSH], 1);
    __syncthreads();
    for (int i = tid; i < nb; i += 256)
        if (lh[i]) atomicAdd(&ghist[i], lh[i]);
}

// (2) exclusive scan of bucket counts (nb <= 512)
__global__ void scan_buckets(const int* __restrict__ hist, int* __restrict__ base,
                             int* __restrict__ cur, int nb, int n_edges) {
    __shared__ int tmp[512];
    int t = threadIdx.x;
    int v = (t < nb) ? hist[t] : 0;
    tmp[t] = v;
    __syncthreads();
    for (int off = 1; off < 512; off <<= 1) {
        int u = (t >= off) ? tmp[t - off] : 0;
        __syncthreads();
        tmp[t] += u;
        __syncthreads();
    }
    if (t < nb) {
        base[t] = tmp[t] - v;
        cur[t] = tmp[t] - v;
    }
    if (t == 0) base[nb] = n_edges;
}

// (3) LDS counting sort of a 4096-edge chunk into bucket-contiguous ebuf runs
__global__ __launch_bounds__(512) void bin_edges_lds(
    const int* __restrict__ src, const int* __restrict__ dst,
    int* __restrict__ bkt_cur, uint2* __restrict__ ebuf, int n_edges, int nb) {
    __shared__ int hist[512];    // counts, later global base
    __shared__ int hbase[513];   // exclusive scan (local)
    __shared__ int hcur[512];
    __shared__ uint2 sorted[EPW];
    int tid = threadIdx.x;
    int chunk0 = blockIdx.x * EPW;
    int cnt = min(EPW, n_edges - chunk0);
    hist[tid] = 0;
    __syncthreads();
    for (int i = tid; i < cnt; i += 512) atomicAdd(&hist[dst[chunk0 + i] >> NBSH], 1);
    __syncthreads();
    int v = hist[tid];
    hbase[tid] = v;
    __syncthreads();
    for (int off = 1; off < 512; off <<= 1) {
        int u = (tid >= off) ? hbase[tid - off] : 0;
        __syncthreads();
        hbase[tid] += u;
        __syncthreads();
    }
    int excl = hbase[tid] - v;
    __syncthreads();
    hbase[tid] = excl;
    hcur[tid] = excl;
    if (tid == 511) hbase[512] = excl + v;   // == cnt
    __syncthreads();
    // scatter into LDS, bucket-sorted
    for (int i = tid; i < cnt; i += 512) {
        int s = src[chunk0 + i];
        int d = dst[chunk0 + i];
        int p = atomicAdd(&hcur[d >> NBSH], 1);
        sorted[p] = make_uint2((unsigned)s, (unsigned)d);
    }
    __syncthreads();
    // reserve global bucket slices (contiguous per bucket across chunks)
    int cntb = hbase[tid + 1] - hbase[tid];
    int gb = 0;
    if (tid < nb && cntb > 0) gb = atomicAdd(&bkt_cur[tid], cntb);
    hist[tid] = gb;
    __syncthreads();
    // copy out: consecutive i within a bucket run -> consecutive global pos
    for (int i = tid; i < cnt; i += 512) {
        uint2 ed = sorted[i];
        int b = (int)(ed.y >> NBSH);
        ebuf[hist[b] + (i - hbase[b])] = ed;
    }
}

// (4) per-bucket degree count, LDS atomics only
__global__ void bucket_degi(const uint2* __restrict__ ebuf, const int* __restrict__ bkt_base,
                            int* __restrict__ degi, int n_nodes) {
    __shared__ int ld[128];
    int b = blockIdx.x, tid = threadIdx.x;
    int lo = b << NBSH;
    if (tid < 128) ld[tid] = 0;
    __syncthreads();
    int s = bkt_base[b], t = bkt_base[b + 1];
    for (int i = s + tid; i < t; i += 256) atomicAdd(&ld[(int)ebuf[i].y - lo], 1);
    __syncthreads();
    int hi = min(lo + 128, n_nodes);
    if (tid < hi - lo) degi[lo + tid] = ld[tid];
}

// (5) degi scan: 3-phase (unchanged from R5, cursor write dropped)
__global__ void scan_local(const int* __restrict__ degi, int* __restrict__ loc,
                           int* __restrict__ bsum, int n) {
    __shared__ int tmp[256];
    int i = blockIdx.x * 256 + threadIdx.x;
    int v = (i < n) ? degi[i] : 0;
    tmp[threadIdx.x] = v;
    __syncthreads();
    for (int off = 1; off < 256; off <<= 1) {
        int t = (threadIdx.x >= off) ? tmp[threadIdx.x - off] : 0;
        __syncthreads();
        tmp[threadIdx.x] += t;
        __syncthreads();
    }
    if (i < n) loc[i] = tmp[threadIdx.x] - v;
    if (threadIdx.x == 255) bsum[blockIdx.x] = tmp[255];
}

__global__ void scan_block(int* __restrict__ bsum, int nblk) {
    __shared__ int tmp[256];
    int v = (threadIdx.x < nblk) ? bsum[threadIdx.x] : 0;
    tmp[threadIdx.x] = v;
    __syncthreads();
    for (int off = 1; off < 256; off <<= 1) {
        int t = (threadIdx.x >= off) ? tmp[threadIdx.x - off] : 0;
        __syncthreads();
        tmp[threadIdx.x] += t;
        __syncthreads();
    }
    if (threadIdx.x < nblk) bsum[threadIdx.x] = tmp[threadIdx.x] - v;
}

__global__ void scan_add(const int* __restrict__ loc, const int* __restrict__ bsum,
                         int* __restrict__ row_start, int n, int n_edges) {
    int i = blockIdx.x * 256 + threadIdx.x;
    if (i < n) row_start[i] = loc[i] + bsum[blockIdx.x];
    if (i == 0) row_start[n] = n_edges;
}

// (6) per-bucket col scatter with LDS cursors; writes confined to ~8KB window
__global__ void scatter2(const uint2* __restrict__ ebuf, const int* __restrict__ bkt_base,
                         const int* __restrict__ row_start, int* __restrict__ col,
                         int n_nodes) {
    __shared__ int lcur[128];
    int b = blockIdx.x, tid = threadIdx.x;
    int lo = b << NBSH;
    int hi = min(lo + 128, n_nodes);
    if (tid < hi - lo) lcur[tid] = row_start[lo + tid];
    __syncthreads();
    int s = bkt_base[b], t = bkt_base[b + 1];
    for (int i = s + tid; i < t; i += 256) {
        uint2 ed = ebuf[i];
        int p = atomicAdd(&lcur[(int)ed.y - lo], 1);
        col[p] = (int)ed.x;
    }
}

// ---------------- conversions / weight prep ----------------
__global__ void convert_x(const float* __restrict__ x, unsigned short* __restrict__ xb,
                          int n4) {
    int t = blockIdx.x * blockDim.x + threadIdx.x;
    if (t >= n4) return;
    float4 v = reinterpret_cast<const float4*>(x)[t];
    uint2 o;
    o.x = (unsigned)f2b(v.x) | ((unsigned)f2b(v.y) << 16);
    o.y = (unsigned)f2b(v.z) | ((unsigned)f2b(v.w) << 16);
    reinterpret_cast<uint2*>(xb)[t] = o;
}

__global__ void build_bt(const float* __restrict__ Wl, const float* __restrict__ Wr,
                         unsigned short* __restrict__ Bt, int KA) {
    int KTOT = 2 * KA;
    int idx = blockIdx.x * blockDim.x + threadIdx.x;
    if (idx >= 128 * KTOT) return;
    int n = idx / KTOT, k = idx % KTOT;
    float v = (k < KA) ? Wl[k * 128 + n] : Wr[(k - KA) * 128 + n];
    Bt[idx] = f2b(v);
}

__global__ void cat_kernel(const float* __restrict__ Wl_age, const float* __restrict__ Wl_sex,
                           const float* __restrict__ Wl_eth, const float* __restrict__ Wr_age,
                           const float* __restrict__ Wr_sex, const float* __restrict__ Wr_eth,
                           const float* __restrict__ b_age, const float* __restrict__ b_sex,
                           const float* __restrict__ b_eth, float* __restrict__ Wl_cat,
                           float* __restrict__ Wr_cat, float* __restrict__ b_cat) {
    int idx = blockIdx.x * blockDim.x + threadIdx.x;
    if (idx < 128 * 28) {
        int k = idx / 28, j = idx % 28;
        float vl, vr;
        if (j < 21) {
            vl = Wl_age[k * 21 + j];
            vr = Wr_age[k * 21 + j];
        } else if (j < 23) {
            vl = Wl_sex[k * 2 + (j - 21)];
            vr = Wr_sex[k * 2 + (j - 21)];
        } else {
            vl = Wl_eth[k * 5 + (j - 23)];
            vr = Wr_eth[k * 5 + (j - 23)];
        }
        Wl_cat[idx] = vl;
        Wr_cat[idx] = vr;
    }
    if (idx < 28) {
        b_cat[idx] = (idx < 21) ? b_age[idx] : (idx < 23) ? b_sex[idx - 21] : b_eth[idx - 23];
    }
}

// ---------------- bf16 gather aggregation ----------------
// K=128: wave per node; col batch-loaded once per 64 edges, shfl-broadcast;
// 4 independent row accumulators for ILP.
__global__ void agg128_bf(const unsigned short* __restrict__ feat,
                          const int* __restrict__ row_start, const int* __restrict__ col,
                          unsigned short* __restrict__ mean, int n_nodes) {
    int wave = (blockIdx.x * blockDim.x + threadIdx.x) >> 6;
    int lane = threadIdx.x & 63;
    if (wave >= n_nodes) return;
    int s0 = row_start[wave];
    int deg = row_start[wave + 1] - s0;
    const unsigned* f2 = reinterpret_cast<const unsigned*>(feat);
    float a0 = 0.f, a1 = 0.f, b0 = 0.f, b1 = 0.f;
    float c0 = 0.f, c1 = 0.f, d0 = 0.f, d1 = 0.f;
    for (int base = 0; base < deg; base += 64) {
        int blk = min(64, deg - base);
        int cv = col[s0 + base + min(lane, blk - 1)];
        int i = 0;
        for (; i + 3 < blk; i += 4) {
            int e0 = __shfl(cv, i), e1 = __shfl(cv, i + 1);
            int e2 = __shfl(cv, i + 2), e3 = __shfl(cv, i + 3);
            unsigned u0 = f2[(size_t)e0 * 64 + lane];
            unsigned u1 = f2[(size_t)e1 * 64 + lane];
            unsigned u2 = f2[(size_t)e2 * 64 + lane];
            unsigned u3 = f2[(size_t)e3 * 64 + lane];
            a0 += b2f((unsigned short)(u0 & 0xffff)); a1 += b2f((unsigned short)(u0 >> 16));
            b0 += b2f((unsigned short)(u1 & 0xffff)); b1 += b2f((unsigned short)(u1 >> 16));
            c0 += b2f((unsigned short)(u2 & 0xffff)); c1 += b2f((unsigned short)(u2 >> 16));
            d0 += b2f((unsigned short)(u3 & 0xffff)); d1 += b2f((unsigned short)(u3 >> 16));
        }
        for (; i < blk; ++i) {
            int e0 = __shfl(cv, i);
            unsigned u0 = f2[(size_t)e0 * 64 + lane];
            a0 += b2f((unsigned short)(u0 & 0xffff)); a1 += b2f((unsigned short)(u0 >> 16));
        }
    }
    float inv = (deg > 0) ? 1.0f / (float)deg : 0.0f;
    float sA = (a0 + b0) + (c0 + d0);
    float sB = (a1 + b1) + (c1 + d1);
    unsigned o = (unsigned)f2b(sA * inv) | ((unsigned)f2b(sB * inv) << 16);
    reinterpret_cast<unsigned*>(mean)[(size_t)wave * 64 + lane] = o;
}

__global__ void agg64_bf(const unsigned short* __restrict__ feat,
                         const int* __restrict__ row_start, const int* __restrict__ col,
                         unsigned short* __restrict__ mean, int n_nodes) {
    int wave = (blockIdx.x * blockDim.x + threadIdx.x) >> 6;
    int lane = threadIdx.x & 63;
    if (wave >= n_nodes) return;
    int sub = lane >> 5;
    int lp = lane & 31;
    int s0 = row_start[wave];
    int s1 = row_start[wave + 1];
    const unsigned* f2 = reinterpret_cast<const unsigned*>(feat);
    float a0 = 0.f, a1 = 0.f;
    for (int e = s0 + sub; e < s1; e += 2) {
        unsigned u = f2[(size_t)col[e] * 32 + lp];
        a0 += b2f((unsigned short)(u & 0xffff));
        a1 += b2f((unsigned short)(u >> 16));
    }
    a0 += __shfl_down(a0, 32);
    a1 += __shfl_down(a1, 32);
    if (sub == 0) {
        int deg = s1 - s0;
        float inv = (deg > 0) ? 1.0f / (float)deg : 0.0f;
        unsigned o = (unsigned)f2b(a0 * inv) | ((unsigned)f2b(a1 * inv) << 16);
        reinterpret_cast<unsigned*>(mean)[(size_t)wave * 32 + lp] = o;
    }
}

// ---------------- MFMA layer GEMM ----------------
template <int KTOT, int KA>
__global__ __launch_bounds__(256) void mfma_layer(
    const unsigned short* __restrict__ A0, const unsigned short* __restrict__ A1,
    const unsigned short* __restrict__ Bt, const float* __restrict__ bias,
    unsigned short* __restrict__ out, int n_nodes) {
    constexpr int KC = KTOT / 64;
    __shared__ __align__(16) unsigned short sA[64][72];
    __shared__ __align__(16) unsigned short sB[128][72];
    int node0 = blockIdx.x * 64;
    int tid = threadIdx.x;
    int w = tid >> 6, lane = tid & 63;
    f32x4 acc[8] = {};
    for (int kc = 0; kc < KC; ++kc) {
        const unsigned short* Asrc;
        int kbase, aw;
        if (kc * 64 < KA) { Asrc = A0; kbase = kc * 64; aw = KA; }
        else              { Asrc = A1; kbase = kc * 64 - KA; aw = KTOT - KA; }
        {
            int nd = tid >> 2, k16 = (tid & 3) * 16;
            uint4 v0 = {0, 0, 0, 0}, v1 = {0, 0, 0, 0};
            int gn = node0 + nd;
            if (gn < n_nodes) {
                const uint4* src = reinterpret_cast<const uint4*>(Asrc + (size_t)gn * aw + kbase + k16);
                v0 = src[0];
                v1 = src[1];
            }
            uint4* dst = reinterpret_cast<uint4*>(&sA[nd][k16]);
            dst[0] = v0;
            dst[1] = v1;
        }
        {
            int n = tid >> 1, k32 = (tid & 1) * 32;
            const uint4* src = reinterpret_cast<const uint4*>(Bt + (size_t)n * KTOT + kc * 64 + k32);
            uint4* dst = reinterpret_cast<uint4*>(&sB[n][k32]);
            dst[0] = src[0];
            dst[1] = src[1];
            dst[2] = src[2];
            dst[3] = src[3];
        }
        __syncthreads();
#pragma unroll
        for (int ks = 0; ks < 2; ++ks) {
            int kl = ks * 32 + (lane >> 4) * 8;
            bf16x8 af = *reinterpret_cast<const bf16x8*>(&sA[w * 16 + (lane & 15)][kl]);
#pragma unroll
            for (int t = 0; t < 8; ++t) {
                bf16x8 bfr = *reinterpret_cast<const bf16x8*>(&sB[t * 16 + (lane & 15)][kl]);
                acc[t] = __builtin_amdgcn_mfma_f32_16x16x32_bf16(af, bfr, acc[t], 0, 0, 0);
            }
        }
        __syncthreads();
    }
    int r0 = w * 16, cq = lane >> 4, cr = lane & 15;
#pragma unroll
    for (int t = 0; t < 8; ++t) {
        int colj = t * 16 + cr;
        float bv = bias[colj];
#pragma unroll
        for (int i = 0; i < 4; ++i) {
            int node = node0 + r0 + cq * 4 + i;
            if (node < n_nodes) {
                float v = fmaxf(acc[t][i] + bv, 0.0f);
                out[(size_t)node * 128 + colj] = f2b(v);
            }
        }
    }
}

// ---------------- heads ----------------
__global__ void proj_kernel(const unsigned short* __restrict__ h,
                            const float* __restrict__ Wl_cat, float* __restrict__ p,
                            int n_nodes) {
    const int NPB = 4;
    int node0 = blockIdx.x * NPB;
    __shared__ float sh[NPB][128];
    for (int idx = threadIdx.x; idx < NPB * 128; idx += blockDim.x) {
        int n = idx >> 7, k = idx & 127;
        int node = node0 + n;
        if (node < n_nodes) sh[n][k] = b2f(h[(size_t)node * 128 + k]);
    }
    __syncthreads();
    int n = threadIdx.x >> 5, j = threadIdx.x & 31;
    int node = node0 + n;
    if (node >= n_nodes) return;
    float acc = 0.f;
    if (j < 28)
        for (int k = 0; k < 128; k++) acc += sh[n][k] * Wl_cat[k * 28 + j];
    p[(size_t)node * 32 + j] = acc;
}

__global__ void agg_gather32(const float* __restrict__ p, const int* __restrict__ row_start,
                             const int* __restrict__ col, float* __restrict__ meanp,
                             int n_nodes) {
    int gid = blockIdx.x * blockDim.x + threadIdx.x;
    int node = gid >> 5;
    int j = gid & 31;
    if (node >= n_nodes) return;
    int s0 = row_start[node];
    int s1 = row_start[node + 1];
    float a = 0.f, b = 0.f;
    int e = s0;
    for (; e + 1 < s1; e += 2) {
        a += p[(size_t)col[e] * 32 + j];
        b += p[(size_t)col[e + 1] * 32 + j];
    }
    if (e < s1) a += p[(size_t)col[e] * 32 + j];
    int deg = s1 - s0;
    float inv = (deg > 0) ? 1.0f / (float)deg : 0.0f;
    meanp[(size_t)node * 32 + j] = (a + b) * inv;
}

__global__ void head_out_kernel(const unsigned short* __restrict__ h,
                                const float* __restrict__ meanp,
                                const float* __restrict__ Wr_cat, const float* __restrict__ b_cat,
                                float* __restrict__ age, float* __restrict__ sex,
                                float* __restrict__ eth, int n_nodes) {
    const int NPB = 4;
    int node0 = blockIdx.x * NPB;
    __shared__ float sh[NPB][128];
    for (int idx = threadIdx.x; idx < NPB * 128; idx += blockDim.x) {
        int n = idx >> 7, k = idx & 127;
        int node = node0 + n;
        if (node < n_nodes) sh[n][k] = b2f(h[(size_t)node * 128 + k]);
    }
    __syncthreads();
    int n = threadIdx.x >> 5, j = threadIdx.x & 31;
    int node = node0 + n;
    if (node >= n_nodes || j >= 28) return;
    float acc = b_cat[j] + meanp[(size_t)node * 32 + j];
    for (int k = 0; k < 128; k++) acc += sh[n][k] * Wr_cat[k * 28 + j];
    if (j < 21)
        age[(size_t)node * 21 + j] = acc;
    else if (j < 23)
        sex[(size_t)node * 2 + (j - 21)] = acc;
    else
        eth[(size_t)node * 5 + (j - 23)] = acc;
}

extern "C" void kernel_launch(void* const* d_in, const int* in_sizes, int n_in,
                              void* d_out, int out_size, void* d_ws, size_t ws_size,
                              hipStream_t stream) {
    const float* x        = (const float*)d_in[0];
    const int*   edge_src = (const int*)d_in[1];
    const int*   edge_dst = (const int*)d_in[2];
    const float* Wl_1 = (const float*)d_in[3];
    const float* Wr_1 = (const float*)d_in[4];
    const float* b_1  = (const float*)d_in[5];
    const float* Wl_2 = (const float*)d_in[6];
    const float* Wr_2 = (const float*)d_in[7];
    const float* b_2  = (const float*)d_in[8];
    const float* Wl_3 = (const float*)d_in[9];
    const float* Wr_3 = (const float*)d_in[10];
    const float* b_3  = (const float*)d_in[11];
    const float* Wl_age = (const float*)d_in[12];
    const float* Wr_age = (const float*)d_in[13];
    const float* b_age  = (const float*)d_in[14];
    const float* Wl_sex = (const float*)d_in[15];
    const float* Wr_sex = (const float*)d_in[16];
    const float* b_sex  = (const float*)d_in[17];
    const float* Wl_eth = (const float*)d_in[18];
    const float* Wr_eth = (const float*)d_in[19];
    const float* b_eth  = (const float*)d_in[20];

    const int n_nodes = in_sizes[0] / 64;   // 50000
    const int n_edges = in_sizes[1];        // 800000

    // ---- workspace layout ----
    char* ws = (char*)d_ws;
    int*            degi      = (int*)(ws + 0);                  // 200192
    int*            row_start = (int*)(ws + 200192);             // 200192
    int*            col       = (int*)(ws + 600576);             // 3200256
    unsigned short* Bt1       = (unsigned short*)(ws + 3800832); // 32768
    unsigned short* Bt2       = (unsigned short*)(ws + 3833600); // 65536
    unsigned short* Bt3       = (unsigned short*)(ws + 3899136); // 65536
    float*          Wl_cat    = (float*)(ws + 3964672);          // 14336
    float*          Wr_cat    = (float*)(ws + 3979008);          // 14336
    float*          b_cat     = (float*)(ws + 3993344);          // 256
    unsigned short* xb        = (unsigned short*)(ws + 3993600); // 6400256
    unsigned short* h_bf      = (unsigned short*)(ws + 10393856);// 12800256
    unsigned short* mean_bf   = (unsigned short*)(ws + 23194112);// 12800256
    float*          p         = (float*)(ws + 35994368);         // 6400256  (head phase)
    float*          meanp     = (float*)(ws + 42394624);         // 6400256  (head phase)
    int*            scan_loc  = (int*)(ws + 48794880);           // 200192
    int*            scan_bsum = (int*)(ws + 48995072);           // 1024
    // CSR-build-phase aliases (p / meanp are not live yet):
    uint2*          ebuf      = (uint2*)p;                       // 6.4 MB
    int*            bkt_hist  = (int*)meanp;                     // 512 ints
    int*            bkt_base  = bkt_hist + 512;                  // 513 ints
    int*            bkt_cur   = bkt_hist + 1032;                 // 512 ints

    float* out_age = (float*)d_out;
    float* out_sex = out_age + (size_t)n_nodes * 21;
    float* out_eth = out_sex + (size_t)n_nodes * 2;

    const int nb        = (n_nodes + 127) >> NBSH;          // 391 buckets
    const int nchunks   = (n_edges + EPW - 1) / EPW;        // 196
    const int nblk_scan = (n_nodes + 255) / 256;            // 196

    // ---- CSR build (bucketed, locality-aware) ----
    hipMemsetAsync(bkt_hist, 0, 512 * sizeof(int), stream);
    bucket_hist<<<256, 256, 0, stream>>>(edge_dst, bkt_hist, n_edges, nb);
    scan_buckets<<<1, 512, 0, stream>>>(bkt_hist, bkt_base, bkt_cur, nb, n_edges);
    bin_edges_lds<<<nchunks, 512, 0, stream>>>(edge_src, edge_dst, bkt_cur, ebuf, n_edges, nb);
    bucket_degi<<<nb, 256, 0, stream>>>(ebuf, bkt_base, degi, n_nodes);
    scan_local<<<nblk_scan, 256, 0, stream>>>(degi, scan_loc, scan_bsum, n_nodes);
    scan_block<<<1, 256, 0, stream>>>(scan_bsum, nblk_scan);
    scan_add<<<nblk_scan, 256, 0, stream>>>(scan_loc, scan_bsum, row_start, n_nodes, n_edges);
    scatter2<<<nb, 256, 0, stream>>>(ebuf, bkt_base, row_start, col, n_nodes);

    // ---- weight prep ----
    convert_x<<<(n_nodes * 64 / 4 + 255) / 256, 256, 0, stream>>>(x, xb, n_nodes * 64 / 4);
    build_bt<<<(128 * 128 + 255) / 256, 256, 0, stream>>>(Wl_1, Wr_1, Bt1, 64);
    build_bt<<<(128 * 256 + 255) / 256, 256, 0, stream>>>(Wl_2, Wr_2, Bt2, 128);
    build_bt<<<(128 * 256 + 255) / 256, 256, 0, stream>>>(Wl_3, Wr_3, Bt3, 128);
    cat_kernel<<<(128 * 28 + 255) / 256, 256, 0, stream>>>(
        Wl_age, Wl_sex, Wl_eth, Wr_age, Wr_sex, Wr_eth, b_age, b_sex, b_eth,
        Wl_cat, Wr_cat, b_cat);

    const int agg_grid  = (n_nodes * 64 + 255) / 256;
    const int gemm_grid = (n_nodes + 63) / 64;

    // ---- Layer 1: A = [mean(x)(64) | x(64)] ----
    agg64_bf<<<agg_grid, 256, 0, stream>>>(xb, row_start, col, mean_bf, n_nodes);
    mfma_layer<128, 64><<<gemm_grid, 256, 0, stream>>>(mean_bf, xb, Bt1, b_1, h_bf, n_nodes);

    // ---- Layer 2 ----
    agg128_bf<<<agg_grid, 256, 0, stream>>>(h_bf, row_start, col, mean_bf, n_nodes);
    mfma_layer<256, 128><<<gemm_grid, 256, 0, stream>>>(mean_bf, h_bf, Bt2, b_2, h_bf, n_nodes);

    // ---- Layer 3 ----
    agg128_bf<<<agg_grid, 256, 0, stream>>>(h_bf, row_start, col, mean_bf, n_nodes);
    mfma_layer<256, 128><<<gemm_grid, 256, 0, stream>>>(mean_bf, h_bf, Bt3, b_3, h_bf, n_nodes);

    // ---- Heads ----
    proj_kernel<<<(n_nodes + 3) / 4, 128, 0, stream>>>(h_bf, Wl_cat, p, n_nodes);
    agg_gather32<<<(n_nodes * 32 + 255) / 256, 256, 0, stream>>>(p, row_start, col, meanp, n_nodes);
    head_out_kernel<<<(n_nodes + 3) / 4, 128, 0, stream>>>(
        h_bf, meanp, Wr_cat, b_cat, out_age, out_sex, out_eth, n_nodes);
}

// Round 7
// 348.486 us; speedup vs baseline: 14.9388x; 1.1223x over previous
//
#include <hip/hip_runtime.h>
#include <hip/hip_bf16.h>

// ---------------------------------------------------------------------------
// GraphSAGE x3 (mean aggr, ReLU) + 3 fused heads.  N=50000, E=800000.
// R7: agg64 + agg_gather32 get shfl-broadcast col + 4-deep gather ILP
// (agg64 was 43.5us latency-bound, 2-deep).  Prep kernels fused into one
// dispatch.  CSR build / agg128 / MFMA layers unchanged from R6.
// ---------------------------------------------------------------------------

typedef __attribute__((ext_vector_type(8))) short bf16x8;
typedef __attribute__((ext_vector_type(4))) float f32x4;

#define NBSH 7          // 128 nodes per bucket
#define EPW  4096       // edges per sort chunk

__device__ __forceinline__ unsigned short f2b(float f) {
    __hip_bfloat16 h = __float2bfloat16(f);
    return *reinterpret_cast<unsigned short*>(&h);
}
__device__ __forceinline__ float b2f(unsigned short u) {
    __hip_bfloat16 h;
    *reinterpret_cast<unsigned short*>(&h) = u;
    return __bfloat162float(h);
}

// ---------------- bucketed CSR build ----------------
__global__ void bucket_hist(const int* __restrict__ dst, int* __restrict__ ghist,
                            int n_edges, int nb) {
    __shared__ int lh[512];
    int tid = threadIdx.x;
    for (int i = tid; i < 512; i += 256) lh[i] = 0;
    __syncthreads();
    int stride = gridDim.x * blockDim.x;
    for (int e = blockIdx.x * blockDim.x + tid; e < n_edges; e += stride)
        atomicAdd(&lh[dst[e] >> NBSH], 1);
    __syncthreads();
    for (int i = tid; i < nb; i += 256)
        if (lh[i]) atomicAdd(&ghist[i], lh[i]);
}

__global__ void scan_buckets(const int* __restrict__ hist, int* __restrict__ base,
                             int* __restrict__ cur, int nb, int n_edges) {
    __shared__ int tmp[512];
    int t = threadIdx.x;
    int v = (t < nb) ? hist[t] : 0;
    tmp[t] = v;
    __syncthreads();
    for (int off = 1; off < 512; off <<= 1) {
        int u = (t >= off) ? tmp[t - off] : 0;
        __syncthreads();
        tmp[t] += u;
        __syncthreads();
    }
    if (t < nb) {
        base[t] = tmp[t] - v;
        cur[t] = tmp[t] - v;
    }
    if (t == 0) base[nb] = n_edges;
}

__global__ __launch_bounds__(512) void bin_edges_lds(
    const int* __restrict__ src, const int* __restrict__ dst,
    int* __restrict__ bkt_cur, uint2* __restrict__ ebuf, int n_edges, int nb) {
    __shared__ int hist[512];
    __shared__ int hbase[513];
    __shared__ int hcur[512];
    __shared__ uint2 sorted[EPW];
    int tid = threadIdx.x;
    int chunk0 = blockIdx.x * EPW;
    int cnt = min(EPW, n_edges - chunk0);
    hist[tid] = 0;
    __syncthreads();
    for (int i = tid; i < cnt; i += 512) atomicAdd(&hist[dst[chunk0 + i] >> NBSH], 1);
    __syncthreads();
    int v = hist[tid];
    hbase[tid] = v;
    __syncthreads();
    for (int off = 1; off < 512; off <<= 1) {
        int u = (tid >= off) ? hbase[tid - off] : 0;
        __syncthreads();
        hbase[tid] += u;
        __syncthreads();
    }
    int excl = hbase[tid] - v;
    __syncthreads();
    hbase[tid] = excl;
    hcur[tid] = excl;
    if (tid == 511) hbase[512] = excl + v;
    __syncthreads();
    for (int i = tid; i < cnt; i += 512) {
        int s = src[chunk0 + i];
        int d = dst[chunk0 + i];
        int p = atomicAdd(&hcur[d >> NBSH], 1);
        sorted[p] = make_uint2((unsigned)s, (unsigned)d);
    }
    __syncthreads();
    int cntb = hbase[tid + 1] - hbase[tid];
    int gb = 0;
    if (tid < nb && cntb > 0) gb = atomicAdd(&bkt_cur[tid], cntb);
    hist[tid] = gb;
    __syncthreads();
    for (int i = tid; i < cnt; i += 512) {
        uint2 ed = sorted[i];
        int b = (int)(ed.y >> NBSH);
        ebuf[hist[b] + (i - hbase[b])] = ed;
    }
}

__global__ void bucket_degi(const uint2* __restrict__ ebuf, const int* __restrict__ bkt_base,
                            int* __restrict__ degi, int n_nodes) {
    __shared__ int ld[128];
    int b = blockIdx.x, tid = threadIdx.x;
    int lo = b << NBSH;
    if (tid < 128) ld[tid] = 0;
    __syncthreads();
    int s = bkt_base[b], t = bkt_base[b + 1];
    for (int i = s + tid; i < t; i += 256) atomicAdd(&ld[(int)ebuf[i].y - lo], 1);
    __syncthreads();
    int hi = min(lo + 128, n_nodes);
    if (tid < hi - lo) degi[lo + tid] = ld[tid];
}

__global__ void scan_local(const int* __restrict__ degi, int* __restrict__ loc,
                           int* __restrict__ bsum, int n) {
    __shared__ int tmp[256];
    int i = blockIdx.x * 256 + threadIdx.x;
    int v = (i < n) ? degi[i] : 0;
    tmp[threadIdx.x] = v;
    __syncthreads();
    for (int off = 1; off < 256; off <<= 1) {
        int t = (threadIdx.x >= off) ? tmp[threadIdx.x - off] : 0;
        __syncthreads();
        tmp[threadIdx.x] += t;
        __syncthreads();
    }
    if (i < n) loc[i] = tmp[threadIdx.x] - v;
    if (threadIdx.x == 255) bsum[blockIdx.x] = tmp[255];
}

__global__ void scan_block(int* __restrict__ bsum, int nblk) {
    __shared__ int tmp[256];
    int v = (threadIdx.x < nblk) ? bsum[threadIdx.x] : 0;
    tmp[threadIdx.x] = v;
    __syncthreads();
    for (int off = 1; off < 256; off <<= 1) {
        int t = (threadIdx.x >= off) ? tmp[threadIdx.x - off] : 0;
        __syncthreads();
        tmp[threadIdx.x] += t;
        __syncthreads();
    }
    if (threadIdx.x < nblk) bsum[threadIdx.x] = tmp[threadIdx.x] - v;
}

__global__ void scan_add(const int* __restrict__ loc, const int* __restrict__ bsum,
                         int* __restrict__ row_start, int n, int n_edges) {
    int i = blockIdx.x * 256 + threadIdx.x;
    if (i < n) row_start[i] = loc[i] + bsum[blockIdx.x];
    if (i == 0) row_start[n] = n_edges;
}

__global__ void scatter2(const uint2* __restrict__ ebuf, const int* __restrict__ bkt_base,
                         const int* __restrict__ row_start, int* __restrict__ col,
                         int n_nodes) {
    __shared__ int lcur[128];
    int b = blockIdx.x, tid = threadIdx.x;
    int lo = b << NBSH;
    int hi = min(lo + 128, n_nodes);
    if (tid < hi - lo) lcur[tid] = row_start[lo + tid];
    __syncthreads();
    int s = bkt_base[b], t = bkt_base[b + 1];
    for (int i = s + tid; i < t; i += 256) {
        uint2 ed = ebuf[i];
        int p = atomicAdd(&lcur[(int)ed.y - lo], 1);
        col[p] = (int)ed.x;
    }
}

// ---------------- fused prep: convert_x + 3x build_bt + cat ----------------
__device__ __forceinline__ void bt_body(const float* __restrict__ Wl,
                                        const float* __restrict__ Wr,
                                        unsigned short* __restrict__ Bt,
                                        int KA, int idx) {
    int KTOT = 2 * KA;
    if (idx >= 128 * KTOT) return;
    int n = idx / KTOT, k = idx % KTOT;
    float v = (k < KA) ? Wl[k * 128 + n] : Wr[(k - KA) * 128 + n];
    Bt[idx] = f2b(v);
}

__global__ void prep_all(const float* __restrict__ x, unsigned short* __restrict__ xb, int n4,
                         const float* __restrict__ Wl1, const float* __restrict__ Wr1,
                         unsigned short* __restrict__ Bt1,
                         const float* __restrict__ Wl2, const float* __restrict__ Wr2,
                         unsigned short* __restrict__ Bt2,
                         const float* __restrict__ Wl3, const float* __restrict__ Wr3,
                         unsigned short* __restrict__ Bt3,
                         const float* __restrict__ Wl_age, const float* __restrict__ Wl_sex,
                         const float* __restrict__ Wl_eth,
                         const float* __restrict__ Wr_age, const float* __restrict__ Wr_sex,
                         const float* __restrict__ Wr_eth,
                         const float* __restrict__ b_age, const float* __restrict__ b_sex,
                         const float* __restrict__ b_eth,
                         float* __restrict__ Wl_cat, float* __restrict__ Wr_cat,
                         float* __restrict__ b_cat) {
    int nbx = (n4 + 255) / 256;       // convert_x blocks
    int b = blockIdx.x;
    if (b < nbx) {
        int t = b * 256 + threadIdx.x;
        if (t < n4) {
            float4 v = reinterpret_cast<const float4*>(x)[t];
            uint2 o;
            o.x = (unsigned)f2b(v.x) | ((unsigned)f2b(v.y) << 16);
            o.y = (unsigned)f2b(v.z) | ((unsigned)f2b(v.w) << 16);
            reinterpret_cast<uint2*>(xb)[t] = o;
        }
        return;
    }
    b -= nbx;
    if (b < 64)  { bt_body(Wl1, Wr1, Bt1, 64,  b * 256 + threadIdx.x); return; }
    b -= 64;
    if (b < 128) { bt_body(Wl2, Wr2, Bt2, 128, b * 256 + threadIdx.x); return; }
    b -= 128;
    if (b < 128) { bt_body(Wl3, Wr3, Bt3, 128, b * 256 + threadIdx.x); return; }
    b -= 128;
    {   // cat: 14 blocks cover 128*28
        int idx = b * 256 + threadIdx.x;
        if (idx < 128 * 28) {
            int k = idx / 28, j = idx % 28;
            float vl, vr;
            if (j < 21) {
                vl = Wl_age[k * 21 + j];
                vr = Wr_age[k * 21 + j];
            } else if (j < 23) {
                vl = Wl_sex[k * 2 + (j - 21)];
                vr = Wr_sex[k * 2 + (j - 21)];
            } else {
                vl = Wl_eth[k * 5 + (j - 23)];
                vr = Wr_eth[k * 5 + (j - 23)];
            }
            Wl_cat[idx] = vl;
            Wr_cat[idx] = vr;
        }
        if (idx < 28)
            b_cat[idx] = (idx < 21) ? b_age[idx] : (idx < 23) ? b_sex[idx - 21] : b_eth[idx - 23];
    }
}

// ---------------- bf16 gather aggregation ----------------
// K=128: wave per node; col batch-loaded (64), shfl-broadcast; 4-deep ILP.
__global__ void agg128_bf(const unsigned short* __restrict__ feat,
                          const int* __restrict__ row_start, const int* __restrict__ col,
                          unsigned short* __restrict__ mean, int n_nodes) {
    int wave = (blockIdx.x * blockDim.x + threadIdx.x) >> 6;
    int lane = threadIdx.x & 63;
    if (wave >= n_nodes) return;
    int s0 = row_start[wave];
    int deg = row_start[wave + 1] - s0;
    const unsigned* f2 = reinterpret_cast<const unsigned*>(feat);
    float a0 = 0.f, a1 = 0.f, b0 = 0.f, b1 = 0.f;
    float c0 = 0.f, c1 = 0.f, d0 = 0.f, d1 = 0.f;
    for (int base = 0; base < deg; base += 64) {
        int blk = min(64, deg - base);
        int cv = col[s0 + base + min(lane, blk - 1)];
        int i = 0;
        for (; i + 3 < blk; i += 4) {
            int e0 = __shfl(cv, i), e1 = __shfl(cv, i + 1);
            int e2 = __shfl(cv, i + 2), e3 = __shfl(cv, i + 3);
            unsigned u0 = f2[(size_t)e0 * 64 + lane];
            unsigned u1 = f2[(size_t)e1 * 64 + lane];
            unsigned u2 = f2[(size_t)e2 * 64 + lane];
            unsigned u3 = f2[(size_t)e3 * 64 + lane];
            a0 += b2f((unsigned short)(u0 & 0xffff)); a1 += b2f((unsigned short)(u0 >> 16));
            b0 += b2f((unsigned short)(u1 & 0xffff)); b1 += b2f((unsigned short)(u1 >> 16));
            c0 += b2f((unsigned short)(u2 & 0xffff)); c1 += b2f((unsigned short)(u2 >> 16));
            d0 += b2f((unsigned short)(u3 & 0xffff)); d1 += b2f((unsigned short)(u3 >> 16));
        }
        for (; i < blk; ++i) {
            int e0 = __shfl(cv, i);
            unsigned u0 = f2[(size_t)e0 * 64 + lane];
            a0 += b2f((unsigned short)(u0 & 0xffff)); a1 += b2f((unsigned short)(u0 >> 16));
        }
    }
    float inv = (deg > 0) ? 1.0f / (float)deg : 0.0f;
    float sA = (a0 + b0) + (c0 + d0);
    float sB = (a1 + b1) + (c1 + d1);
    unsigned o = (unsigned)f2b(sA * inv) | ((unsigned)f2b(sB * inv) << 16);
    reinterpret_cast<unsigned*>(mean)[(size_t)wave * 64 + lane] = o;
}

// K=64 (32 uints/row): wave per node; half-waves take alternating 4-edge
// groups; 4 independent accumulators per half = 8 outstanding loads/wave.
__global__ void agg64_bf(const unsigned short* __restrict__ feat,
                         const int* __restrict__ row_start, const int* __restrict__ col,
                         unsigned short* __restrict__ mean, int n_nodes) {
    int wave = (blockIdx.x * blockDim.x + threadIdx.x) >> 6;
    int lane = threadIdx.x & 63;
    if (wave >= n_nodes) return;
    int half = lane >> 5;
    int lp = lane & 31;
    int s0 = row_start[wave];
    int deg = row_start[wave + 1] - s0;
    const unsigned* f2 = reinterpret_cast<const unsigned*>(feat);
    float a0 = 0.f, a1 = 0.f, b0 = 0.f, b1 = 0.f;
    float c0 = 0.f, c1 = 0.f, d0 = 0.f, d1 = 0.f;
    for (int base = 0; base < deg; base += 64) {
        int blk = min(64, deg - base);
        int cv = col[s0 + base + min(lane, blk - 1)];
        int nfull = blk & ~7;
        for (int i = half * 4; i < nfull; i += 8) {
            int e0 = __shfl(cv, i), e1 = __shfl(cv, i + 1);
            int e2 = __shfl(cv, i + 2), e3 = __shfl(cv, i + 3);
            unsigned u0 = f2[(size_t)e0 * 32 + lp];
            unsigned u1 = f2[(size_t)e1 * 32 + lp];
            unsigned u2 = f2[(size_t)e2 * 32 + lp];
            unsigned u3 = f2[(size_t)e3 * 32 + lp];
            a0 += b2f((unsigned short)(u0 & 0xffff)); a1 += b2f((unsigned short)(u0 >> 16));
            b0 += b2f((unsigned short)(u1 & 0xffff)); b1 += b2f((unsigned short)(u1 >> 16));
            c0 += b2f((unsigned short)(u2 & 0xffff)); c1 += b2f((unsigned short)(u2 >> 16));
            d0 += b2f((unsigned short)(u3 & 0xffff)); d1 += b2f((unsigned short)(u3 >> 16));
        }
        int tstart = nfull + half * 4;
        int tend = min(blk, tstart + 4);
        for (int i = tstart; i < tend; ++i) {
            int e0 = __shfl(cv, i);
            unsigned u0 = f2[(size_t)e0 * 32 + lp];
            a0 += b2f((unsigned short)(u0 & 0xffff)); a1 += b2f((unsigned short)(u0 >> 16));
        }
    }
    float sA = (a0 + b0) + (c0 + d0);
    float sB = (a1 + b1) + (c1 + d1);
    sA += __shfl_down(sA, 32);
    sB += __shfl_down(sB, 32);
    if (half == 0) {
        float inv = (deg > 0) ? 1.0f / (float)deg : 0.0f;
        unsigned o = (unsigned)f2b(sA * inv) | ((unsigned)f2b(sB * inv) << 16);
        reinterpret_cast<unsigned*>(mean)[(size_t)wave * 32 + lp] = o;
    }
}

// ---------------- MFMA layer GEMM ----------------
template <int KTOT, int KA>
__global__ __launch_bounds__(256) void mfma_layer(
    const unsigned short* __restrict__ A0, const unsigned short* __restrict__ A1,
    const unsigned short* __restrict__ Bt, const float* __restrict__ bias,
    unsigned short* __restrict__ out, int n_nodes) {
    constexpr int KC = KTOT / 64;
    __shared__ __align__(16) unsigned short sA[64][72];
    __shared__ __align__(16) unsigned short sB[128][72];
    int node0 = blockIdx.x * 64;
    int tid = threadIdx.x;
    int w = tid >> 6, lane = tid & 63;
    f32x4 acc[8] = {};
    for (int kc = 0; kc < KC; ++kc) {
        const unsigned short* Asrc;
        int kbase, aw;
        if (kc * 64 < KA) { Asrc = A0; kbase = kc * 64; aw = KA; }
        else              { Asrc = A1; kbase = kc * 64 - KA; aw = KTOT - KA; }
        {
            int nd = tid >> 2, k16 = (tid & 3) * 16;
            uint4 v0 = {0, 0, 0, 0}, v1 = {0, 0, 0, 0};
            int gn = node0 + nd;
            if (gn < n_nodes) {
                const uint4* src = reinterpret_cast<const uint4*>(Asrc + (size_t)gn * aw + kbase + k16);
                v0 = src[0];
                v1 = src[1];
            }
            uint4* dst = reinterpret_cast<uint4*>(&sA[nd][k16]);
            dst[0] = v0;
            dst[1] = v1;
        }
        {
            int n = tid >> 1, k32 = (tid & 1) * 32;
            const uint4* src = reinterpret_cast<const uint4*>(Bt + (size_t)n * KTOT + kc * 64 + k32);
            uint4* dst = reinterpret_cast<uint4*>(&sB[n][k32]);
            dst[0] = src[0];
            dst[1] = src[1];
            dst[2] = src[2];
            dst[3] = src[3];
        }
        __syncthreads();
#pragma unroll
        for (int ks = 0; ks < 2; ++ks) {
            int kl = ks * 32 + (lane >> 4) * 8;
            bf16x8 af = *reinterpret_cast<const bf16x8*>(&sA[w * 16 + (lane & 15)][kl]);
#pragma unroll
            for (int t = 0; t < 8; ++t) {
                bf16x8 bfr = *reinterpret_cast<const bf16x8*>(&sB[t * 16 + (lane & 15)][kl]);
                acc[t] = __builtin_amdgcn_mfma_f32_16x16x32_bf16(af, bfr, acc[t], 0, 0, 0);
            }
        }
        __syncthreads();
    }
    int r0 = w * 16, cq = lane >> 4, cr = lane & 15;
#pragma unroll
    for (int t = 0; t < 8; ++t) {
        int colj = t * 16 + cr;
        float bv = bias[colj];
#pragma unroll
        for (int i = 0; i < 4; ++i) {
            int node = node0 + r0 + cq * 4 + i;
            if (node < n_nodes) {
                float v = fmaxf(acc[t][i] + bv, 0.0f);
                out[(size_t)node * 128 + colj] = f2b(v);
            }
        }
    }
}

// ---------------- heads ----------------
__global__ void proj_kernel(const unsigned short* __restrict__ h,
                            const float* __restrict__ Wl_cat, float* __restrict__ p,
                            int n_nodes) {
    const int NPB = 4;
    int node0 = blockIdx.x * NPB;
    __shared__ float sh[NPB][128];
    for (int idx = threadIdx.x; idx < NPB * 128; idx += blockDim.x) {
        int n = idx >> 7, k = idx & 127;
        int node = node0 + n;
        if (node < n_nodes) sh[n][k] = b2f(h[(size_t)node * 128 + k]);
    }
    __syncthreads();
    int n = threadIdx.x >> 5, j = threadIdx.x & 31;
    int node = node0 + n;
    if (node >= n_nodes) return;
    float acc = 0.f;
    if (j < 28)
        for (int k = 0; k < 128; k++) acc += sh[n][k] * Wl_cat[k * 28 + j];
    p[(size_t)node * 32 + j] = acc;
}

// 32-lane group per node; col batched 32 at a time, shfl-broadcast, 4-deep.
__global__ void agg_gather32(const float* __restrict__ p, const int* __restrict__ row_start,
                             const int* __restrict__ col, float* __restrict__ meanp,
                             int n_nodes) {
    int node = (blockIdx.x * blockDim.x + threadIdx.x) >> 5;
    int lane = threadIdx.x & 63;
    int lp = lane & 31;
    int grpbase = lane & 32;
    if (node >= n_nodes) return;
    int s0 = row_start[node];
    int deg = row_start[node + 1] - s0;
    float a = 0.f, b = 0.f, c = 0.f, d = 0.f;
    for (int base = 0; base < deg; base += 32) {
        int blk = min(32, deg - base);
        int cv = col[s0 + base + min(lp, blk - 1)];
        int i = 0;
        for (; i + 3 < blk; i += 4) {
            int e0 = __shfl(cv, grpbase + i),     e1 = __shfl(cv, grpbase + i + 1);
            int e2 = __shfl(cv, grpbase + i + 2), e3 = __shfl(cv, grpbase + i + 3);
            a += p[(size_t)e0 * 32 + lp];
            b += p[(size_t)e1 * 32 + lp];
            c += p[(size_t)e2 * 32 + lp];
            d += p[(size_t)e3 * 32 + lp];
        }
        for (; i < blk; ++i) {
            int e0 = __shfl(cv, grpbase + i);
            a += p[(size_t)e0 * 32 + lp];
        }
    }
    float inv = (deg > 0) ? 1.0f / (float)deg : 0.0f;
    meanp[(size_t)node * 32 + lp] = ((a + b) + (c + d)) * inv;
}

__global__ void head_out_kernel(const unsigned short* __restrict__ h,
                                const float* __restrict__ meanp,
                                const float* __restrict__ Wr_cat, const float* __restrict__ b_cat,
                                float* __restrict__ age, float* __restrict__ sex,
                                float* __restrict__ eth, int n_nodes) {
    const int NPB = 4;
    int node0 = blockIdx.x * NPB;
    __shared__ float sh[NPB][128];
    for (int idx = threadIdx.x; idx < NPB * 128; idx += blockDim.x) {
        int n = idx >> 7, k = idx & 127;
        int node = node0 + n;
        if (node < n_nodes) sh[n][k] = b2f(h[(size_t)node * 128 + k]);
    }
    __syncthreads();
    int n = threadIdx.x >> 5, j = threadIdx.x & 31;
    int node = node0 + n;
    if (node >= n_nodes || j >= 28) return;
    float acc = b_cat[j] + meanp[(size_t)node * 32 + j];
    for (int k = 0; k < 128; k++) acc += sh[n][k] * Wr_cat[k * 28 + j];
    if (j < 21)
        age[(size_t)node * 21 + j] = acc;
    else if (j < 23)
        sex[(size_t)node * 2 + (j - 21)] = acc;
    else
        eth[(size_t)node * 5 + (j - 23)] = acc;
}

extern "C" void kernel_launch(void* const* d_in, const int* in_sizes, int n_in,
                              void* d_out, int out_size, void* d_ws, size_t ws_size,
                              hipStream_t stream) {
    const float* x        = (const float*)d_in[0];
    const int*   edge_src = (const int*)d_in[1];
    const int*   edge_dst = (const int*)d_in[2];
    const float* Wl_1 = (const float*)d_in[3];
    const float* Wr_1 = (const float*)d_in[4];
    const float* b_1  = (const float*)d_in[5];
    const float* Wl_2 = (const float*)d_in[6];
    const float* Wr_2 = (const float*)d_in[7];
    const float* b_2  = (const float*)d_in[8];
    const float* Wl_3 = (const float*)d_in[9];
    const float* Wr_3 = (const float*)d_in[10];
    const float* b_3  = (const float*)d_in[11];
    const float* Wl_age = (const float*)d_in[12];
    const float* Wr_age = (const float*)d_in[13];
    const float* b_age  = (const float*)d_in[14];
    const float* Wl_sex = (const float*)d_in[15];
    const float* Wr_sex = (const float*)d_in[16];
    const float* b_sex  = (const float*)d_in[17];
    const float* Wl_eth = (const float*)d_in[18];
    const float* Wr_eth = (const float*)d_in[19];
    const float* b_eth  = (const float*)d_in[20];

    const int n_nodes = in_sizes[0] / 64;   // 50000
    const int n_edges = in_sizes[1];        // 800000

    // ---- workspace layout ----
    char* ws = (char*)d_ws;
    int*            degi      = (int*)(ws + 0);                  // 200192
    int*            row_start = (int*)(ws + 200192);             // 200192
    int*            col       = (int*)(ws + 600576);             // 3200256
    unsigned short* Bt1       = (unsigned short*)(ws + 3800832); // 32768
    unsigned short* Bt2       = (unsigned short*)(ws + 3833600); // 65536
    unsigned short* Bt3       = (unsigned short*)(ws + 3899136); // 65536
    float*          Wl_cat    = (float*)(ws + 3964672);          // 14336
    float*          Wr_cat    = (float*)(ws + 3979008);          // 14336
    float*          b_cat     = (float*)(ws + 3993344);          // 256
    unsigned short* xb        = (unsigned short*)(ws + 3993600); // 6400256
    unsigned short* h_bf      = (unsigned short*)(ws + 10393856);// 12800256
    unsigned short* mean_bf   = (unsigned short*)(ws + 23194112);// 12800256
    float*          p         = (float*)(ws + 35994368);         // 6400256  (head phase)
    float*          meanp     = (float*)(ws + 42394624);         // 6400256  (head phase)
    int*            scan_loc  = (int*)(ws + 48794880);           // 200192
    int*            scan_bsum = (int*)(ws + 48995072);           // 1024
    // CSR-build-phase aliases (p / meanp not live yet):
    uint2*          ebuf      = (uint2*)p;                       // 6.4 MB
    int*            bkt_hist  = (int*)meanp;                     // 512 ints
    int*            bkt_base  = bkt_hist + 512;                  // 513 ints
    int*            bkt_cur   = bkt_hist + 1032;                 // 512 ints

    float* out_age = (float*)d_out;
    float* out_sex = out_age + (size_t)n_nodes * 21;
    float* out_eth = out_sex + (size_t)n_nodes * 2;

    const int nb        = (n_nodes + 127) >> NBSH;          // 391 buckets
    const int nchunks   = (n_edges + EPW - 1) / EPW;        // 196
    const int nblk_scan = (n_nodes + 255) / 256;            // 196
    const int n4        = n_nodes * 64 / 4;                 // 800000

    // ---- CSR build (bucketed, locality-aware) ----
    hipMemsetAsync(bkt_hist, 0, 512 * sizeof(int), stream);
    bucket_hist<<<256, 256, 0, stream>>>(edge_dst, bkt_hist, n_edges, nb);
    scan_buckets<<<1, 512, 0, stream>>>(bkt_hist, bkt_base, bkt_cur, nb, n_edges);
    bin_edges_lds<<<nchunks, 512, 0, stream>>>(edge_src, edge_dst, bkt_cur, ebuf, n_edges, nb);
    bucket_degi<<<nb, 256, 0, stream>>>(ebuf, bkt_base, degi, n_nodes);
    scan_local<<<nblk_scan, 256, 0, stream>>>(degi, scan_loc, scan_bsum, n_nodes);
    scan_block<<<1, 256, 0, stream>>>(scan_bsum, nblk_scan);
    scan_add<<<nblk_scan, 256, 0, stream>>>(scan_loc, scan_bsum, row_start, n_nodes, n_edges);
    scatter2<<<nb, 256, 0, stream>>>(ebuf, bkt_base, row_start, col, n_nodes);

    // ---- fused prep (convert_x + Bt1..3 + cat) ----
    {
        int grid = (n4 + 255) / 256 + 64 + 128 + 128 + 14;
        prep_all<<<grid, 256, 0, stream>>>(
            x, xb, n4, Wl_1, Wr_1, Bt1, Wl_2, Wr_2, Bt2, Wl_3, Wr_3, Bt3,
            Wl_age, Wl_sex, Wl_eth, Wr_age, Wr_sex, Wr_eth, b_age, b_sex, b_eth,
            Wl_cat, Wr_cat, b_cat);
    }

    const int agg_grid  = (n_nodes * 64 + 255) / 256;
    const int gemm_grid = (n_nodes + 63) / 64;

    // ---- Layer 1: A = [mean(x)(64) | x(64)] ----
    agg64_bf<<<agg_grid, 256, 0, stream>>>(xb, row_start, col, mean_bf, n_nodes);
    mfma_layer<128, 64><<<gemm_grid, 256, 0, stream>>>(mean_bf, xb, Bt1, b_1, h_bf, n_nodes);

    // ---- Layer 2 ----
    agg128_bf<<<agg_grid, 256, 0, stream>>>(h_bf, row_start, col, mean_bf, n_nodes);
    mfma_layer<256, 128><<<gemm_grid, 256, 0, stream>>>(mean_bf, h_bf, Bt2, b_2, h_bf, n_nodes);

    // ---- Layer 3 ----
    agg128_bf<<<agg_grid, 256, 0, stream>>>(h_bf, row_start, col, mean_bf, n_nodes);
    mfma_layer<256, 128><<<gemm_grid, 256, 0, stream>>>(mean_bf, h_bf, Bt3, b_3, h_bf, n_nodes);

    // ---- Heads ----
    proj_kernel<<<(n_nodes + 3) / 4, 128, 0, stream>>>(h_bf, Wl_cat, p, n_nodes);
    agg_gather32<<<(n_nodes * 32 + 255) / 256, 256, 0, stream>>>(p, row_start, col, meanp, n_nodes);
    head_out_kernel<<<(n_nodes + 3) / 4, 128, 0, stream>>>(
        h_bf, meanp, Wr_cat, b_cat, out_age, out_sex, out_eth, n_nodes);
}

// Round 8
// 330.441 us; speedup vs baseline: 15.7546x; 1.0546x over previous
//
#include <hip/hip_runtime.h>
#include <hip/hip_bf16.h>

// ---------------------------------------------------------------------------
// GraphSAGE x3 (mean aggr, ReLU) + 3 fused heads.  N=50000, E=800000.
// R8: structural fusion, numerics frozen.
//  - sort_bucket = bucket_degi + scans + scatter2 (5 dispatches -> 1)
//  - proj2 computes p=h@Wl AND q=h@Wr+b (fp32); head_final = agg(p)+q+scatter
//  - prep_all zeroes bkt_hist (drops in-graph memset)
//  13 dispatches total (was 18).
// ---------------------------------------------------------------------------

typedef __attribute__((ext_vector_type(8))) short bf16x8;
typedef __attribute__((ext_vector_type(4))) float f32x4;

#define NBSH 7          // 128 nodes per bucket
#define EPW  4096       // edges per sort chunk

__device__ __forceinline__ unsigned short f2b(float f) {
    __hip_bfloat16 h = __float2bfloat16(f);
    return *reinterpret_cast<unsigned short*>(&h);
}
__device__ __forceinline__ float b2f(unsigned short u) {
    __hip_bfloat16 h;
    *reinterpret_cast<unsigned short*>(&h) = u;
    return __bfloat162float(h);
}

// ---------------- bucketed CSR build ----------------
__global__ void bucket_hist(const int* __restrict__ dst, int* __restrict__ ghist,
                            int n_edges, int nb) {
    __shared__ int lh[512];
    int tid = threadIdx.x;
    for (int i = tid; i < 512; i += 256) lh[i] = 0;
    __syncthreads();
    int stride = gridDim.x * blockDim.x;
    for (int e = blockIdx.x * blockDim.x + tid; e < n_edges; e += stride)
        atomicAdd(&lh[dst[e] >> NBSH], 1);
    __syncthreads();
    for (int i = tid; i < nb; i += 256)
        if (lh[i]) atomicAdd(&ghist[i], lh[i]);
}

__global__ void scan_buckets(const int* __restrict__ hist, int* __restrict__ base,
                             int* __restrict__ cur, int nb, int n_edges) {
    __shared__ int tmp[512];
    int t = threadIdx.x;
    int v = (t < nb) ? hist[t] : 0;
    tmp[t] = v;
    __syncthreads();
    for (int off = 1; off < 512; off <<= 1) {
        int u = (t >= off) ? tmp[t - off] : 0;
        __syncthreads();
        tmp[t] += u;
        __syncthreads();
    }
    if (t < nb) {
        base[t] = tmp[t] - v;
        cur[t] = tmp[t] - v;
    }
    if (t == 0) base[nb] = n_edges;
}

__global__ __launch_bounds__(512) void bin_edges_lds(
    const int* __restrict__ src, const int* __restrict__ dst,
    int* __restrict__ bkt_cur, uint2* __restrict__ ebuf, int n_edges, int nb) {
    __shared__ int hist[512];
    __shared__ int hbase[513];
    __shared__ int hcur[512];
    __shared__ uint2 sorted[EPW];
    int tid = threadIdx.x;
    int chunk0 = blockIdx.x * EPW;
    int cnt = min(EPW, n_edges - chunk0);
    hist[tid] = 0;
    __syncthreads();
    for (int i = tid; i < cnt; i += 512) atomicAdd(&hist[dst[chunk0 + i] >> NBSH], 1);
    __syncthreads();
    int v = hist[tid];
    hbase[tid] = v;
    __syncthreads();
    for (int off = 1; off < 512; off <<= 1) {
        int u = (tid >= off) ? hbase[tid - off] : 0;
        __syncthreads();
        hbase[tid] += u;
        __syncthreads();
    }
    int excl = hbase[tid] - v;
    __syncthreads();
    hbase[tid] = excl;
    hcur[tid] = excl;
    if (tid == 511) hbase[512] = excl + v;
    __syncthreads();
    for (int i = tid; i < cnt; i += 512) {
        int s = src[chunk0 + i];
        int d = dst[chunk0 + i];
        int p = atomicAdd(&hcur[d >> NBSH], 1);
        sorted[p] = make_uint2((unsigned)s, (unsigned)d);
    }
    __syncthreads();
    int cntb = hbase[tid + 1] - hbase[tid];
    int gb = 0;
    if (tid < nb && cntb > 0) gb = atomicAdd(&bkt_cur[tid], cntb);
    hist[tid] = gb;
    __syncthreads();
    for (int i = tid; i < cnt; i += 512) {
        uint2 ed = sorted[i];
        int b = (int)(ed.y >> NBSH);
        ebuf[hist[b] + (i - hbase[b])] = ed;
    }
}

// Fused: per-bucket degree count + local scan -> row_start, then LDS-cursor
// scatter of col.  Two passes over the bucket's ebuf slice, no LDS edge buf.
__global__ void sort_bucket(const uint2* __restrict__ ebuf, const int* __restrict__ bkt_base,
                            int* __restrict__ row_start, int* __restrict__ col,
                            int n_nodes, int n_edges) {
    __shared__ int hist[128];
    __shared__ int sc[128];
    __shared__ int hcur[128];
    int b = blockIdx.x, tid = threadIdx.x;
    int lo = b << NBSH;
    if (tid < 128) hist[tid] = 0;
    __syncthreads();
    int s = bkt_base[b], t = bkt_base[b + 1];
    for (int i = s + tid; i < t; i += 256) atomicAdd(&hist[(int)ebuf[i].y - lo], 1);
    __syncthreads();
    if (tid < 128) sc[tid] = hist[tid];
    __syncthreads();
    for (int off = 1; off < 128; off <<= 1) {
        int u = (tid < 128 && tid >= off) ? sc[tid - off] : 0;
        __syncthreads();
        if (tid < 128) sc[tid] += u;
        __syncthreads();
    }
    if (tid < 128) {
        int excl = sc[tid] - hist[tid];
        hcur[tid] = excl;
        int node = lo + tid;
        if (node < n_nodes) row_start[node] = s + excl;
    }
    if (b == 0 && tid == 0) row_start[n_nodes] = n_edges;
    __syncthreads();
    for (int i = s + tid; i < t; i += 256) {
        uint2 ed = ebuf[i];
        int p = atomicAdd(&hcur[(int)ed.y - lo], 1);
        col[s + p] = (int)ed.x;
    }
}

// ---------------- fused prep: convert_x + 3x build_bt + cat + zero hist ----
__device__ __forceinline__ void bt_body(const float* __restrict__ Wl,
                                        const float* __restrict__ Wr,
                                        unsigned short* __restrict__ Bt,
                                        int KA, int idx) {
    int KTOT = 2 * KA;
    if (idx >= 128 * KTOT) return;
    int n = idx / KTOT, k = idx % KTOT;
    float v = (k < KA) ? Wl[k * 128 + n] : Wr[(k - KA) * 128 + n];
    Bt[idx] = f2b(v);
}

__global__ void prep_all(const float* __restrict__ x, unsigned short* __restrict__ xb, int n4,
                         const float* __restrict__ Wl1, const float* __restrict__ Wr1,
                         unsigned short* __restrict__ Bt1,
                         const float* __restrict__ Wl2, const float* __restrict__ Wr2,
                         unsigned short* __restrict__ Bt2,
                         const float* __restrict__ Wl3, const float* __restrict__ Wr3,
                         unsigned short* __restrict__ Bt3,
                         const float* __restrict__ Wl_age, const float* __restrict__ Wl_sex,
                         const float* __restrict__ Wl_eth,
                         const float* __restrict__ Wr_age, const float* __restrict__ Wr_sex,
                         const float* __restrict__ Wr_eth,
                         const float* __restrict__ b_age, const float* __restrict__ b_sex,
                         const float* __restrict__ b_eth,
                         float* __restrict__ Wl_cat, float* __restrict__ Wr_cat,
                         float* __restrict__ b_cat, int* __restrict__ bkt_hist) {
    int nbx = (n4 + 255) / 256;       // convert_x blocks
    int b = blockIdx.x;
    if (b < nbx) {
        int t = b * 256 + threadIdx.x;
        if (t < n4) {
            float4 v = reinterpret_cast<const float4*>(x)[t];
            uint2 o;
            o.x = (unsigned)f2b(v.x) | ((unsigned)f2b(v.y) << 16);
            o.y = (unsigned)f2b(v.z) | ((unsigned)f2b(v.w) << 16);
            reinterpret_cast<uint2*>(xb)[t] = o;
        }
        return;
    }
    b -= nbx;
    if (b < 64)  { bt_body(Wl1, Wr1, Bt1, 64,  b * 256 + threadIdx.x); return; }
    b -= 64;
    if (b < 128) { bt_body(Wl2, Wr2, Bt2, 128, b * 256 + threadIdx.x); return; }
    b -= 128;
    if (b < 128) { bt_body(Wl3, Wr3, Bt3, 128, b * 256 + threadIdx.x); return; }
    b -= 128;
    if (b < 14) {   // cat: 14 blocks cover 128*28
        int idx = b * 256 + threadIdx.x;
        if (idx < 128 * 28) {
            int k = idx / 28, j = idx % 28;
            float vl, vr;
            if (j < 21) {
                vl = Wl_age[k * 21 + j];
                vr = Wr_age[k * 21 + j];
            } else if (j < 23) {
                vl = Wl_sex[k * 2 + (j - 21)];
                vr = Wr_sex[k * 2 + (j - 21)];
            } else {
                vl = Wl_eth[k * 5 + (j - 23)];
                vr = Wr_eth[k * 5 + (j - 23)];
            }
            Wl_cat[idx] = vl;
            Wr_cat[idx] = vr;
        }
        if (idx < 28)
            b_cat[idx] = (idx < 21) ? b_age[idx] : (idx < 23) ? b_sex[idx - 21] : b_eth[idx - 23];
        return;
    }
    // final block: zero the 512-int bucket histogram
    bkt_hist[threadIdx.x] = 0;
    bkt_hist[256 + threadIdx.x] = 0;
}

// ---------------- bf16 gather aggregation ----------------
// K=128: wave per node; col batch-loaded (64), shfl-broadcast; 4-deep ILP.
__global__ void agg128_bf(const unsigned short* __restrict__ feat,
                          const int* __restrict__ row_start, const int* __restrict__ col,
                          unsigned short* __restrict__ mean, int n_nodes) {
    int wave = (blockIdx.x * blockDim.x + threadIdx.x) >> 6;
    int lane = threadIdx.x & 63;
    if (wave >= n_nodes) return;
    int s0 = row_start[wave];
    int deg = row_start[wave + 1] - s0;
    const unsigned* f2 = reinterpret_cast<const unsigned*>(feat);
    float a0 = 0.f, a1 = 0.f, b0 = 0.f, b1 = 0.f;
    float c0 = 0.f, c1 = 0.f, d0 = 0.f, d1 = 0.f;
    for (int base = 0; base < deg; base += 64) {
        int blk = min(64, deg - base);
        int cv = col[s0 + base + min(lane, blk - 1)];
        int i = 0;
        for (; i + 3 < blk; i += 4) {
            int e0 = __shfl(cv, i), e1 = __shfl(cv, i + 1);
            int e2 = __shfl(cv, i + 2), e3 = __shfl(cv, i + 3);
            unsigned u0 = f2[(size_t)e0 * 64 + lane];
            unsigned u1 = f2[(size_t)e1 * 64 + lane];
            unsigned u2 = f2[(size_t)e2 * 64 + lane];
            unsigned u3 = f2[(size_t)e3 * 64 + lane];
            a0 += b2f((unsigned short)(u0 & 0xffff)); a1 += b2f((unsigned short)(u0 >> 16));
            b0 += b2f((unsigned short)(u1 & 0xffff)); b1 += b2f((unsigned short)(u1 >> 16));
            c0 += b2f((unsigned short)(u2 & 0xffff)); c1 += b2f((unsigned short)(u2 >> 16));
            d0 += b2f((unsigned short)(u3 & 0xffff)); d1 += b2f((unsigned short)(u3 >> 16));
        }
        for (; i < blk; ++i) {
            int e0 = __shfl(cv, i);
            unsigned u0 = f2[(size_t)e0 * 64 + lane];
            a0 += b2f((unsigned short)(u0 & 0xffff)); a1 += b2f((unsigned short)(u0 >> 16));
        }
    }
    float inv = (deg > 0) ? 1.0f / (float)deg : 0.0f;
    float sA = (a0 + b0) + (c0 + d0);
    float sB = (a1 + b1) + (c1 + d1);
    unsigned o = (unsigned)f2b(sA * inv) | ((unsigned)f2b(sB * inv) << 16);
    reinterpret_cast<unsigned*>(mean)[(size_t)wave * 64 + lane] = o;
}

// K=64 (32 uints/row): wave per node; half-waves alternate 4-edge groups.
__global__ void agg64_bf(const unsigned short* __restrict__ feat,
                         const int* __restrict__ row_start, const int* __restrict__ col,
                         unsigned short* __restrict__ mean, int n_nodes) {
    int wave = (blockIdx.x * blockDim.x + threadIdx.x) >> 6;
    int lane = threadIdx.x & 63;
    if (wave >= n_nodes) return;
    int half = lane >> 5;
    int lp = lane & 31;
    int s0 = row_start[wave];
    int deg = row_start[wave + 1] - s0;
    const unsigned* f2 = reinterpret_cast<const unsigned*>(feat);
    float a0 = 0.f, a1 = 0.f, b0 = 0.f, b1 = 0.f;
    float c0 = 0.f, c1 = 0.f, d0 = 0.f, d1 = 0.f;
    for (int base = 0; base < deg; base += 64) {
        int blk = min(64, deg - base);
        int cv = col[s0 + base + min(lane, blk - 1)];
        int nfull = blk & ~7;
        for (int i = half * 4; i < nfull; i += 8) {
            int e0 = __shfl(cv, i), e1 = __shfl(cv, i + 1);
            int e2 = __shfl(cv, i + 2), e3 = __shfl(cv, i + 3);
            unsigned u0 = f2[(size_t)e0 * 32 + lp];
            unsigned u1 = f2[(size_t)e1 * 32 + lp];
            unsigned u2 = f2[(size_t)e2 * 32 + lp];
            unsigned u3 = f2[(size_t)e3 * 32 + lp];
            a0 += b2f((unsigned short)(u0 & 0xffff)); a1 += b2f((unsigned short)(u0 >> 16));
            b0 += b2f((unsigned short)(u1 & 0xffff)); b1 += b2f((unsigned short)(u1 >> 16));
            c0 += b2f((unsigned short)(u2 & 0xffff)); c1 += b2f((unsigned short)(u2 >> 16));
            d0 += b2f((unsigned short)(u3 & 0xffff)); d1 += b2f((unsigned short)(u3 >> 16));
        }
        int tstart = nfull + half * 4;
        int tend = min(blk, tstart + 4);
        for (int i = tstart; i < tend; ++i) {
            int e0 = __shfl(cv, i);
            unsigned u0 = f2[(size_t)e0 * 32 + lp];
            a0 += b2f((unsigned short)(u0 & 0xffff)); a1 += b2f((unsigned short)(u0 >> 16));
        }
    }
    float sA = (a0 + b0) + (c0 + d0);
    float sB = (a1 + b1) + (c1 + d1);
    sA += __shfl_down(sA, 32);
    sB += __shfl_down(sB, 32);
    if (half == 0) {
        float inv = (deg > 0) ? 1.0f / (float)deg : 0.0f;
        unsigned o = (unsigned)f2b(sA * inv) | ((unsigned)f2b(sB * inv) << 16);
        reinterpret_cast<unsigned*>(mean)[(size_t)wave * 32 + lp] = o;
    }
}

// ---------------- MFMA layer GEMM ----------------
template <int KTOT, int KA>
__global__ __launch_bounds__(256) void mfma_layer(
    const unsigned short* __restrict__ A0, const unsigned short* __restrict__ A1,
    const unsigned short* __restrict__ Bt, const float* __restrict__ bias,
    unsigned short* __restrict__ out, int n_nodes) {
    constexpr int KC = KTOT / 64;
    __shared__ __align__(16) unsigned short sA[64][72];
    __shared__ __align__(16) unsigned short sB[128][72];
    int node0 = blockIdx.x * 64;
    int tid = threadIdx.x;
    int w = tid >> 6, lane = tid & 63;
    f32x4 acc[8] = {};
    for (int kc = 0; kc < KC; ++kc) {
        const unsigned short* Asrc;
        int kbase, aw;
        if (kc * 64 < KA) { Asrc = A0; kbase = kc * 64; aw = KA; }
        else              { Asrc = A1; kbase = kc * 64 - KA; aw = KTOT - KA; }
        {
            int nd = tid >> 2, k16 = (tid & 3) * 16;
            uint4 v0 = {0, 0, 0, 0}, v1 = {0, 0, 0, 0};
            int gn = node0 + nd;
            if (gn < n_nodes) {
                const uint4* src = reinterpret_cast<const uint4*>(Asrc + (size_t)gn * aw + kbase + k16);
                v0 = src[0];
                v1 = src[1];
            }
            uint4* dst = reinterpret_cast<uint4*>(&sA[nd][k16]);
            dst[0] = v0;
            dst[1] = v1;
        }
        {
            int n = tid >> 1, k32 = (tid & 1) * 32;
            const uint4* src = reinterpret_cast<const uint4*>(Bt + (size_t)n * KTOT + kc * 64 + k32);
            uint4* dst = reinterpret_cast<uint4*>(&sB[n][k32]);
            dst[0] = src[0];
            dst[1] = src[1];
            dst[2] = src[2];
            dst[3] = src[3];
        }
        __syncthreads();
#pragma unroll
        for (int ks = 0; ks < 2; ++ks) {
            int kl = ks * 32 + (lane >> 4) * 8;
            bf16x8 af = *reinterpret_cast<const bf16x8*>(&sA[w * 16 + (lane & 15)][kl]);
#pragma unroll
            for (int t = 0; t < 8; ++t) {
                bf16x8 bfr = *reinterpret_cast<const bf16x8*>(&sB[t * 16 + (lane & 15)][kl]);
                acc[t] = __builtin_amdgcn_mfma_f32_16x16x32_bf16(af, bfr, acc[t], 0, 0, 0);
            }
        }
        __syncthreads();
    }
    int r0 = w * 16, cq = lane >> 4, cr = lane & 15;
#pragma unroll
    for (int t = 0; t < 8; ++t) {
        int colj = t * 16 + cr;
        float bv = bias[colj];
#pragma unroll
        for (int i = 0; i < 4; ++i) {
            int node = node0 + r0 + cq * 4 + i;
            if (node < n_nodes) {
                float v = fmaxf(acc[t][i] + bv, 0.0f);
                out[(size_t)node * 128 + colj] = f2b(v);
            }
        }
    }
}

// ---------------- heads ----------------
// p[i][j] = h[i,:].Wl_cat[:,j]; q[i][j] = h[i,:].Wr_cat[:,j] + b_cat[j]
// (fp32, j<28; cols 28..31 zeroed).  Same op order as R7's proj/head_out.
__global__ void proj2_kernel(const unsigned short* __restrict__ h,
                             const float* __restrict__ Wl_cat, const float* __restrict__ Wr_cat,
                             const float* __restrict__ b_cat,
                             float* __restrict__ p, float* __restrict__ q, int n_nodes) {
    const int NPB = 4;
    int node0 = blockIdx.x * NPB;
    __shared__ float sh[NPB][128];
    for (int idx = threadIdx.x; idx < NPB * 128; idx += blockDim.x) {
        int n = idx >> 7, k = idx & 127;
        int node = node0 + n;
        if (node < n_nodes) sh[n][k] = b2f(h[(size_t)node * 128 + k]);
    }
    __syncthreads();
    int n = threadIdx.x >> 5, j = threadIdx.x & 31;
    int node = node0 + n;
    if (node >= n_nodes) return;
    float accp = 0.f;
    float accq = 0.f;
    if (j < 28) {
        accq = b_cat[j];
        for (int k = 0; k < 128; k++) {
            float hv = sh[n][k];
            accp += hv * Wl_cat[k * 28 + j];
            accq += hv * Wr_cat[k * 28 + j];
        }
    }
    p[(size_t)node * 32 + j] = accp;
    q[(size_t)node * 32 + j] = accq;
}

// 32-lane group per node: gather-mean of p + q[node] -> scatter to outputs.
__global__ void head_final(const float* __restrict__ p, const float* __restrict__ q,
                           const int* __restrict__ row_start, const int* __restrict__ col,
                           float* __restrict__ age, float* __restrict__ sex,
                           float* __restrict__ eth, int n_nodes) {
    int node = (blockIdx.x * blockDim.x + threadIdx.x) >> 5;
    int lane = threadIdx.x & 63;
    int lp = lane & 31;
    int grpbase = lane & 32;
    if (node >= n_nodes) return;
    int s0 = row_start[node];
    int deg = row_start[node + 1] - s0;
    float a = 0.f, b = 0.f, c = 0.f, d = 0.f;
    for (int base = 0; base < deg; base += 32) {
        int blk = min(32, deg - base);
        int cv = col[s0 + base + min(lp, blk - 1)];
        int i = 0;
        for (; i + 3 < blk; i += 4) {
            int e0 = __shfl(cv, grpbase + i),     e1 = __shfl(cv, grpbase + i + 1);
            int e2 = __shfl(cv, grpbase + i + 2), e3 = __shfl(cv, grpbase + i + 3);
            a += p[(size_t)e0 * 32 + lp];
            b += p[(size_t)e1 * 32 + lp];
            c += p[(size_t)e2 * 32 + lp];
            d += p[(size_t)e3 * 32 + lp];
        }
        for (; i < blk; ++i) {
            int e0 = __shfl(cv, grpbase + i);
            a += p[(size_t)e0 * 32 + lp];
        }
    }
    float inv = (deg > 0) ? 1.0f / (float)deg : 0.0f;
    float out = ((a + b) + (c + d)) * inv + q[(size_t)node * 32 + lp];
    if (lp < 21)
        age[(size_t)node * 21 + lp] = out;
    else if (lp < 23)
        sex[(size_t)node * 2 + (lp - 21)] = out;
    else if (lp < 28)
        eth[(size_t)node * 5 + (lp - 23)] = out;
}

extern "C" void kernel_launch(void* const* d_in, const int* in_sizes, int n_in,
                              void* d_out, int out_size, void* d_ws, size_t ws_size,
                              hipStream_t stream) {
    const float* x        = (const float*)d_in[0];
    const int*   edge_src = (const int*)d_in[1];
    const int*   edge_dst = (const int*)d_in[2];
    const float* Wl_1 = (const float*)d_in[3];
    const float* Wr_1 = (const float*)d_in[4];
    const float* b_1  = (const float*)d_in[5];
    const float* Wl_2 = (const float*)d_in[6];
    const float* Wr_2 = (const float*)d_in[7];
    const float* b_2  = (const float*)d_in[8];
    const float* Wl_3 = (const float*)d_in[9];
    const float* Wr_3 = (const float*)d_in[10];
    const float* b_3  = (const float*)d_in[11];
    const float* Wl_age = (const float*)d_in[12];
    const float* Wr_age = (const float*)d_in[13];
    const float* b_age  = (const float*)d_in[14];
    const float* Wl_sex = (const float*)d_in[15];
    const float* Wr_sex = (const float*)d_in[16];
    const float* b_sex  = (const float*)d_in[17];
    const float* Wl_eth = (const float*)d_in[18];
    const float* Wr_eth = (const float*)d_in[19];
    const float* b_eth  = (const float*)d_in[20];

    const int n_nodes = in_sizes[0] / 64;   // 50000
    const int n_edges = in_sizes[1];        // 800000

    // ---- workspace layout ----
    char* ws = (char*)d_ws;
    int*            row_start = (int*)(ws + 200192);             // 200192
    int*            col       = (int*)(ws + 600576);             // 3200256
    unsigned short* Bt1       = (unsigned short*)(ws + 3800832); // 32768
    unsigned short* Bt2       = (unsigned short*)(ws + 3833600); // 65536
    unsigned short* Bt3       = (unsigned short*)(ws + 3899136); // 65536
    float*          Wl_cat    = (float*)(ws + 3964672);          // 14336
    float*          Wr_cat    = (float*)(ws + 3979008);          // 14336
    float*          b_cat     = (float*)(ws + 3993344);          // 256
    unsigned short* xb        = (unsigned short*)(ws + 3993600); // 6400256
    unsigned short* h_bf      = (unsigned short*)(ws + 10393856);// 12800256
    unsigned short* mean_bf   = (unsigned short*)(ws + 23194112);// 12800256
    float*          p         = (float*)(ws + 35994368);         // 6400256  (head phase)
    float*          q         = (float*)(ws + 42394624);         // 6400256  (head phase)
    // CSR-build-phase aliases (p / q not live yet):
    uint2*          ebuf      = (uint2*)p;                       // 6.4 MB
    int*            bkt_hist  = (int*)q;                         // 512 ints
    int*            bkt_base  = bkt_hist + 512;                  // 513 ints
    int*            bkt_cur   = bkt_hist + 1032;                 // 512 ints

    float* out_age = (float*)d_out;
    float* out_sex = out_age + (size_t)n_nodes * 21;
    float* out_eth = out_sex + (size_t)n_nodes * 2;

    const int nb      = (n_nodes + 127) >> NBSH;          // 391 buckets
    const int nchunks = (n_edges + EPW - 1) / EPW;        // 196
    const int n4      = n_nodes * 64 / 4;                 // 800000

    // ---- fused prep (convert_x + Bt1..3 + cat + zero bkt_hist) ----
    {
        int grid = (n4 + 255) / 256 + 64 + 128 + 128 + 14 + 1;
        prep_all<<<grid, 256, 0, stream>>>(
            x, xb, n4, Wl_1, Wr_1, Bt1, Wl_2, Wr_2, Bt2, Wl_3, Wr_3, Bt3,
            Wl_age, Wl_sex, Wl_eth, Wr_age, Wr_sex, Wr_eth, b_age, b_sex, b_eth,
            Wl_cat, Wr_cat, b_cat, bkt_hist);
    }

    // ---- CSR build (bucketed, locality-aware) ----
    bucket_hist<<<256, 256, 0, stream>>>(edge_dst, bkt_hist, n_edges, nb);
    scan_buckets<<<1, 512, 0, stream>>>(bkt_hist, bkt_base, bkt_cur, nb, n_edges);
    bin_edges_lds<<<nchunks, 512, 0, stream>>>(edge_src, edge_dst, bkt_cur, ebuf, n_edges, nb);
    sort_bucket<<<nb, 256, 0, stream>>>(ebuf, bkt_base, row_start, col, n_nodes, n_edges);

    const int agg_grid  = (n_nodes * 64 + 255) / 256;
    const int gemm_grid = (n_nodes + 63) / 64;

    // ---- Layer 1: A = [mean(x)(64) | x(64)] ----
    agg64_bf<<<agg_grid, 256, 0, stream>>>(xb, row_start, col, mean_bf, n_nodes);
    mfma_layer<128, 64><<<gemm_grid, 256, 0, stream>>>(mean_bf, xb, Bt1, b_1, h_bf, n_nodes);

    // ---- Layer 2 ----
    agg128_bf<<<agg_grid, 256, 0, stream>>>(h_bf, row_start, col, mean_bf, n_nodes);
    mfma_layer<256, 128><<<gemm_grid, 256, 0, stream>>>(mean_bf, h_bf, Bt2, b_2, h_bf, n_nodes);

    // ---- Layer 3 ----
    agg128_bf<<<agg_grid, 256, 0, stream>>>(h_bf, row_start, col, mean_bf, n_nodes);
    mfma_layer<256, 128><<<gemm_grid, 256, 0, stream>>>(mean_bf, h_bf, Bt3, b_3, h_bf, n_nodes);

    // ---- Heads: p = h@Wl, q = h@Wr+b, then mean(p)+q -> scatter ----
    proj2_kernel<<<(n_nodes + 3) / 4, 128, 0, stream>>>(h_bf, Wl_cat, Wr_cat, b_cat, p, q, n_nodes);
    head_final<<<(n_nodes * 32 + 255) / 256, 256, 0, stream>>>(
        p, q, row_start, col, out_age, out_sex, out_eth, n_nodes);
}